// Round 2
// baseline (3637.864 us; speedup 1.0000x reference)
//
#include <hip/hip_runtime.h>
#include <cstdint>

#define NB    64
#define LIMG  196
#define DIMG  2048
#define RNND  1024
#define EMBD  512
#define TSTEPS 17
#define VOUTD 10003

__device__ __forceinline__ float fast_sig(float x) {
    return 1.f / (1.f + __expf(-x));
}
__device__ __forceinline__ float fast_tanh(float x) {
    float ax = fabsf(x);
    float e  = __expf(2.f * ax);
    float r  = 1.f - 2.f / (e + 1.f);
    return copysignf(r, x);
}

// ---------------------------------------------------------------------------
// Generic tiled GEMM: C[m,n] = sum_k A[m,k]*B[k,n]  (A row-major [M,K], B [K,N])
// Block tile 64x64, K-tile 16, 256 threads, 4x4 register tile per thread.
// direct=1: apply bias/act, write C with row stride ldc (blockIdx.y = m-tile).
// direct=0: split-K partial; blockIdx.z = s, K-range [s*Kc, s*Kc+Kc),
//           writes P slab at C + s*64*N (M must be 64, blockIdx.y = 0).
// ---------------------------------------------------------------------------
__global__ __launch_bounds__(256) void gemm64(
    const float* __restrict__ A, const float* __restrict__ B,
    const float* __restrict__ bias, float* __restrict__ C,
    int N, int K, int Kc, int ldc, int act, int direct)
{
    __shared__ float As[16][64];
    __shared__ float Bs[16][68];

    const int tid = threadIdx.x;
    const int n0  = blockIdx.x * 64;
    const int m0  = blockIdx.y * 64;
    const int s   = blockIdx.z;
    const int kb  = s * Kc;
    const int ke  = min(K, kb + Kc);

    const int tm = (tid >> 4) << 2;   // 0..60
    const int tn = (tid & 15) << 2;   // 0..60

    float acc[4][4];
#pragma unroll
    for (int i = 0; i < 4; i++)
#pragma unroll
        for (int j = 0; j < 4; j++) acc[i][j] = 0.f;

    const int a_m = tid >> 2;         // 0..63
    const int a_k = (tid & 3) << 2;   // 0,4,8,12
    const int b_k = tid >> 4;         // 0..15
    const int b_n = (tid & 15) << 2;  // 0..60
    const bool n4 = ((N & 3) == 0);

    for (int k0 = kb; k0 < ke; k0 += 16) {
        float4 av = *(const float4*)(A + (size_t)(m0 + a_m) * K + (k0 + a_k));
        float4 bv;
        {
            const int nn = n0 + b_n;
            const float* brow = B + (size_t)(k0 + b_k) * N;
            if (n4) {
                bv = (nn < N) ? *(const float4*)(brow + nn) : make_float4(0.f,0.f,0.f,0.f);
            } else {
                bv.x = (nn + 0 < N) ? brow[nn + 0] : 0.f;
                bv.y = (nn + 1 < N) ? brow[nn + 1] : 0.f;
                bv.z = (nn + 2 < N) ? brow[nn + 2] : 0.f;
                bv.w = (nn + 3 < N) ? brow[nn + 3] : 0.f;
            }
        }
        __syncthreads();
        As[a_k + 0][a_m] = av.x;
        As[a_k + 1][a_m] = av.y;
        As[a_k + 2][a_m] = av.z;
        As[a_k + 3][a_m] = av.w;
        *(float4*)&Bs[b_k][b_n] = bv;
        __syncthreads();
#pragma unroll
        for (int k = 0; k < 16; k++) {
            float4 a4 = *(const float4*)&As[k][tm];
            float4 b4 = *(const float4*)&Bs[k][tn];
            acc[0][0] = fmaf(a4.x, b4.x, acc[0][0]);
            acc[0][1] = fmaf(a4.x, b4.y, acc[0][1]);
            acc[0][2] = fmaf(a4.x, b4.z, acc[0][2]);
            acc[0][3] = fmaf(a4.x, b4.w, acc[0][3]);
            acc[1][0] = fmaf(a4.y, b4.x, acc[1][0]);
            acc[1][1] = fmaf(a4.y, b4.y, acc[1][1]);
            acc[1][2] = fmaf(a4.y, b4.z, acc[1][2]);
            acc[1][3] = fmaf(a4.y, b4.w, acc[1][3]);
            acc[2][0] = fmaf(a4.z, b4.x, acc[2][0]);
            acc[2][1] = fmaf(a4.z, b4.y, acc[2][1]);
            acc[2][2] = fmaf(a4.z, b4.z, acc[2][2]);
            acc[2][3] = fmaf(a4.z, b4.w, acc[2][3]);
            acc[3][0] = fmaf(a4.w, b4.x, acc[3][0]);
            acc[3][1] = fmaf(a4.w, b4.y, acc[3][1]);
            acc[3][2] = fmaf(a4.w, b4.z, acc[3][2]);
            acc[3][3] = fmaf(a4.w, b4.w, acc[3][3]);
        }
    }

    if (direct) {
#pragma unroll
        for (int i = 0; i < 4; i++) {
            const int m = m0 + tm + i;
            const size_t row = (size_t)m * ldc;
#pragma unroll
            for (int j = 0; j < 4; j++) {
                const int n = n0 + tn + j;
                if (n < N) {
                    float v = acc[i][j] + (bias ? bias[n] : 0.f);
                    if (act == 1) v = fast_tanh(v);
                    else if (act == 2) v = fast_sig(v);
                    C[row + n] = v;
                }
            }
        }
    } else {
        float* P = C + (size_t)s * 64 * N;
#pragma unroll
        for (int i = 0; i < 4; i++) {
#pragma unroll
            for (int j = 0; j < 4; j++) {
                const int n = n0 + tn + j;
                if (n < N) P[(size_t)(tm + i) * N + n] = acc[i][j];
            }
        }
    }
}

// C[m,n] = act( bias[n] + sum_s P[s][m][n] ),  m in [0,64)
// act: 0 none, 1 tanh, 2 sigmoid, 3 (none for n<1024, sigmoid for n>=1024)
__global__ __launch_bounds__(256) void reduce_partials(
    const float* __restrict__ P, int S, int N,
    const float* __restrict__ bias, float* __restrict__ C, int ldc, int act)
{
    const int idx = blockIdx.x * 256 + threadIdx.x;
    const int total = 64 * N;
    if (idx >= total) return;
    const int m = idx / N;
    const int n = idx - m * N;
    float v = bias ? bias[n] : 0.f;
    for (int s = 0; s < S; s++) v += P[(size_t)s * total + idx];
    if (act == 1) v = fast_tanh(v);
    else if (act == 2) v = fast_sig(v);
    else if (act == 3 && n >= RNND) v = fast_sig(v);
    C[(size_t)m * ldc + n] = v;
}

__global__ __launch_bounds__(256) void mean_img(
    const float* __restrict__ img, float* __restrict__ avg)
{
    const int b = blockIdx.x;
    const int d = blockIdx.y * 256 + threadIdx.x;
    const float* p = img + (size_t)b * LIMG * DIMG + d;
    float s = 0.f;
    for (int l = 0; l < LIMG; l++) s += p[(size_t)l * DIMG];
    avg[(size_t)b * DIMG + d] = s * (1.f / 196.f);
}

__global__ __launch_bounds__(256) void concat_w(
    const float* __restrict__ WU, const float* __restrict__ Wfb,
    float* __restrict__ Wug)
{
    const int idx = blockIdx.x * 256 + threadIdx.x;
    if (idx >= 1024 * 3072) return;
    const int k = idx / 3072;
    const int j = idx - k * 3072;
    Wug[idx] = (j < 1024) ? WU[(size_t)k * 1024 + j] : Wfb[(size_t)k * 2048 + (j - 1024)];
}

__global__ __launch_bounds__(256) void concat_b(
    const float* __restrict__ bU, const float* __restrict__ bfb,
    const float* __restrict__ bih, const float* __restrict__ bhh,
    float* __restrict__ bug, float* __restrict__ bsum)
{
    const int j = blockIdx.x * 256 + threadIdx.x;
    if (j < 3072) bug[j] = (j < 1024) ? bU[j] : bfb[j - 1024];
    if (j < 4096) bsum[j] = bih[j] + bhh[j];
}

// e[b,l] = tanh(Ws[b,l,:] + Uh[b,:]) . Wv + bv    (one wave per (b,l) row)
__global__ __launch_bounds__(256) void attn_e(
    const float* __restrict__ Ws, const float* __restrict__ ug,
    const float* __restrict__ Wv, const float* __restrict__ bv,
    float* __restrict__ e)
{
    const int wv   = (blockIdx.x << 2) + (threadIdx.x >> 6);
    const int lane = threadIdx.x & 63;
    const int b    = wv / LIMG;
    const float* wrow = Ws + (size_t)wv * RNND;
    const float* urow = ug + (size_t)b * 3072;
    float acc = 0.f;
#pragma unroll
    for (int k = lane * 4; k < RNND; k += 256) {
        float4 wq = *(const float4*)(wrow + k);
        float4 uq = *(const float4*)(urow + k);
        float4 vq = *(const float4*)(Wv + k);
        acc += fast_tanh(wq.x + uq.x) * vq.x + fast_tanh(wq.y + uq.y) * vq.y
             + fast_tanh(wq.z + uq.z) * vq.z + fast_tanh(wq.w + uq.w) * vq.w;
    }
#pragma unroll
    for (int off = 32; off > 0; off >>= 1) acc += __shfl_down(acc, off);
    if (lane == 0) e[wv] = acc + bv[0];
}

__global__ __launch_bounds__(256) void softmax_alpha(
    const float* __restrict__ e, float* __restrict__ alpha,
    float* __restrict__ alphas_out, int t)
{
    __shared__ float red[256];
    const int b = blockIdx.x, tid = threadIdx.x;
    const float v = (tid < LIMG) ? e[b * LIMG + tid] : -3.0e38f;
    red[tid] = v; __syncthreads();
    for (int s = 128; s > 0; s >>= 1) {
        if (tid < s) red[tid] = fmaxf(red[tid], red[tid + s]);
        __syncthreads();
    }
    const float mx = red[0]; __syncthreads();
    const float ex = (tid < LIMG) ? __expf(v - mx) : 0.f;
    red[tid] = ex; __syncthreads();
    for (int s = 128; s > 0; s >>= 1) {
        if (tid < s) red[tid] += red[tid + s];
        __syncthreads();
    }
    const float inv = 1.f / red[0];
    if (tid < LIMG) {
        const float a = ex * inv;
        alpha[b * LIMG + tid] = a;
        alphas_out[(size_t)b * (TSTEPS * LIMG) + t * LIMG + tid] = a;
    }
}

// x[b, 0:512] = emb[token], x[b, 512+d] = gate[b,d] * context[b,d]
__global__ __launch_bounds__(128) void assemble_x(
    const float* __restrict__ img, const float* __restrict__ alpha,
    const float* __restrict__ ug, const float* __restrict__ emb,
    const int* __restrict__ captions, float* __restrict__ x, int t)
{
    const int b = blockIdx.x, y = blockIdx.y, tid = threadIdx.x;
    if (y < 4) {
        const int tok = (t == 0) ? 10001 : captions[b * 16 + (t - 1)];
        const int j = y * 128 + tid;
        x[(size_t)b * 2560 + j] = emb[(size_t)tok * EMBD + j];
    } else {
        __shared__ float al[LIMG];
        for (int i = tid; i < LIMG; i += 128) al[i] = alpha[b * LIMG + i];
        __syncthreads();
        const int d = (y - 4) * 128 + tid;
        const float* ib = img + (size_t)b * LIMG * DIMG + d;
        float accv = 0.f;
#pragma unroll 4
        for (int l = 0; l < LIMG; l++) accv = fmaf(al[l], ib[(size_t)l * DIMG], accv);
        const float g = ug[(size_t)b * 3072 + 1024 + d];  // sigmoided gate
        x[(size_t)b * 2560 + EMBD + d] = g * accv;
    }
}

__global__ __launch_bounds__(256) void lstm_cell(
    const float* __restrict__ gates, float* __restrict__ h, float* __restrict__ c)
{
    const int idx = blockIdx.x * 256 + threadIdx.x;  // 64*1024
    const int b = idx >> 10, r = idx & 1023;
    const float* g = gates + (size_t)b * 4096;
    const float ig = fast_sig(g[r]);
    const float fg = fast_sig(g[RNND + r]);
    const float gg = fast_tanh(g[2 * RNND + r]);
    const float og = fast_sig(g[3 * RNND + r]);
    const float cn = fg * c[idx] + ig * gg;
    const float hn = og * fast_tanh(cn);
    c[idx] = cn;
    h[idx] = hn;
}

extern "C" void kernel_launch(void* const* d_in, const int* in_sizes, int n_in,
                              void* d_out, int out_size, void* d_ws, size_t ws_size,
                              hipStream_t stream)
{
    const float* img      = (const float*)d_in[0];
    const int*   captions = (const int*)d_in[1];
    const float* emb      = (const float*)d_in[2];
    const float* Wih      = (const float*)d_in[3];
    const float* Whh      = (const float*)d_in[4];
    const float* bih      = (const float*)d_in[5];
    const float* bhh      = (const float*)d_in[6];
    const float* Wh0      = (const float*)d_in[7];
    const float* bh0      = (const float*)d_in[8];
    const float* Wc0      = (const float*)d_in[9];
    const float* bc0      = (const float*)d_in[10];
    const float* Wfb      = (const float*)d_in[11];
    const float* bfb      = (const float*)d_in[12];
    const float* Wout     = (const float*)d_in[13];
    const float* bout     = (const float*)d_in[14];
    const float* WU       = (const float*)d_in[15];
    const float* bU       = (const float*)d_in[16];
    const float* WW       = (const float*)d_in[17];
    const float* bW       = (const float*)d_in[18];
    const float* Wv       = (const float*)d_in[19];
    const float* bv       = (const float*)d_in[20];

    float* preds      = (float*)d_out;
    float* alphas_out = preds + (size_t)NB * TSTEPS * VOUTD;

    // workspace layout (floats)
    float* w = (float*)d_ws;
    float* Ws    = w; w += (size_t)12544 * 1024;   // 12,845,056
    float* ug    = w; w += (size_t)64 * 3072;      // U_h (0:1024) | gate (1024:3072)
    float* P     = w; w += (size_t)12 * 64 * 4096; // split-K partials
    float* e     = w; w += (size_t)64 * LIMG;
    float* alpha = w; w += (size_t)64 * LIMG;
    float* x     = w; w += (size_t)64 * 2560;
    float* gates = w; w += (size_t)64 * 4096;
    float* h     = w; w += (size_t)64 * RNND;
    float* c     = w; w += (size_t)64 * RNND;
    float* avg   = w; w += (size_t)64 * DIMG;
    float* bsum  = w; w += 4096;
    float* Wug   = w; w += (size_t)1024 * 3072;
    float* bug   = w; w += 3072;

    // ---- precompute ----
    mean_img<<<dim3(NB, 8), 256, 0, stream>>>(img, avg);

    // h0 = tanh(avg @ Wh0 + bh0)
    gemm64<<<dim3(16, 1, 8), 256, 0, stream>>>(avg, Wh0, nullptr, P, 1024, 2048, 256, 0, 0, 0);
    reduce_partials<<<256, 256, 0, stream>>>(P, 8, 1024, bh0, h, 1024, 1);
    // c0 = tanh(avg @ Wc0 + bc0)
    gemm64<<<dim3(16, 1, 8), 256, 0, stream>>>(avg, Wc0, nullptr, P, 1024, 2048, 256, 0, 0, 0);
    reduce_partials<<<256, 256, 0, stream>>>(P, 8, 1024, bc0, c, 1024, 1);

    concat_b<<<16, 256, 0, stream>>>(bU, bfb, bih, bhh, bug, bsum);
    concat_w<<<12288, 256, 0, stream>>>(WU, Wfb, Wug);

    // W_s = img @ WW + bW   [12544, 1024], direct
    gemm64<<<dim3(16, 196, 1), 256, 0, stream>>>(img, WW, bW, Ws, 1024, 2048, 2048, 1024, 0, 1);

    // ---- timestep loop ----
    for (int t = 0; t < TSTEPS; t++) {
        // [U_h | gate] = h @ [WU | Wfb] + [bU | bfb], sigmoid on gate half
        gemm64<<<dim3(48, 1, 8), 256, 0, stream>>>(h, Wug, nullptr, P, 3072, 1024, 128, 0, 0, 0);
        reduce_partials<<<768, 256, 0, stream>>>(P, 8, 3072, bug, ug, 3072, 3);

        attn_e<<<3136, 256, 0, stream>>>(Ws, ug, Wv, bv, e);
        softmax_alpha<<<NB, 256, 0, stream>>>(e, alpha, alphas_out, t);
        assemble_x<<<dim3(NB, 20), 128, 0, stream>>>(img, alpha, ug, emb, captions, x, t);

        // gates = x @ Wih + h @ Whh + (bih+bhh)
        gemm64<<<dim3(64, 1, 8), 256, 0, stream>>>(x, Wih, nullptr, P, 4096, 2560, 320, 0, 0, 0);
        gemm64<<<dim3(64, 1, 4), 256, 0, stream>>>(h, Whh, nullptr, P + (size_t)8 * 64 * 4096,
                                                   4096, 1024, 256, 0, 0, 0);
        reduce_partials<<<1024, 256, 0, stream>>>(P, 12, 4096, bsum, gates, 4096, 0);

        lstm_cell<<<256, 256, 0, stream>>>(gates, h, c);

        // preds[:, t, :] = h @ Wout + bout
        gemm64<<<dim3(157, 1, 4), 256, 0, stream>>>(h, Wout, nullptr, P, VOUTD, 1024, 256, 0, 0, 0);
        reduce_partials<<<2501, 256, 0, stream>>>(P, 4, VOUTD, bout,
                                                  preds + (size_t)t * VOUTD,
                                                  TSTEPS * VOUTD, 0);
    }
}

// Round 3
// 2360.638 us; speedup vs baseline: 1.5411x; 1.5411x over previous
//
#include <hip/hip_runtime.h>
#include <cstdint>

#define NB    64
#define LIMG  196
#define DIMG  2048
#define RNND  1024
#define EMBD  512
#define TSTEPS 17
#define VOUTD 10003

typedef short bf16x8 __attribute__((ext_vector_type(8)));
typedef float f32x4  __attribute__((ext_vector_type(4)));

__device__ __forceinline__ float fast_sig(float x) {
    return 1.f / (1.f + __expf(-x));
}
__device__ __forceinline__ float fast_tanh(float x) {
    float ax = fabsf(x);
    float e  = __expf(2.f * ax);
    float r  = 1.f - 2.f / (e + 1.f);
    return copysignf(r, x);
}
__device__ __forceinline__ void split_bf(float x, short& hi, short& lo) {
    unsigned u  = __float_as_uint(x);
    unsigned hb = u & 0xffff0000u;
    hi = (short)(u >> 16);
    float r = x - __uint_as_float(hb);
    lo = (short)(__float_as_uint(r) >> 16);
}

// ---------------------------------------------------------------------------
// bf16x3 MFMA GEMM: C = A@B + bias, A[M,K] f32, B[K,N] f32, on-the-fly hi/lo
// split (C = Ahi*Bhi + Ahi*Blo + Alo*Bhi, fp32 accum => ~fp32 accuracy).
// Tile 128x128, BK=32, 256 threads (4 waves, 2x2 wave grid, 64x64 per wave).
// pmap=1: output row m -> (m&63)*17 + (m>>6)  (for [t,b] -> [b,t] preds map).
// Requires K % 32 == 0, lda % 4 == 0.
// ---------------------------------------------------------------------------
__global__ __launch_bounds__(256) void gemm_mfma3(
    const float* __restrict__ A, const float* __restrict__ B,
    const float* __restrict__ bias, float* __restrict__ C,
    int M, int N, int K, int lda, int ldb, int ldc, int pmap)
{
    __shared__ short Ah[128 * 40], Al[128 * 40];   // [row][k] k-contiguous
    __shared__ short Bh[128 * 40], Bl[128 * 40];   // [col][k] k-contiguous

    const int tid = threadIdx.x;
    const int n0  = blockIdx.x * 128;
    const int m0  = blockIdx.y * 128;

    const int lane = tid & 63;
    const int w    = tid >> 6;       // wave 0..3
    const int wm   = (w >> 1) * 64;  // wave row offset
    const int wn   = (w & 1) * 64;   // wave col offset
    const int lm   = lane & 15;
    const int lk   = lane >> 4;      // 0..3

    // A staging coords: row r = tid>>1, col chunk cb = (tid&1)*16
    const int ar = tid >> 1;
    const int ac = (tid & 1) * 16;
    // B staging coords: k pair kb = (tid&15)*2, col chunk c8 = (tid>>4)*8
    const int kb = (tid & 15) * 2;
    const int c8 = (tid >> 4) * 8;

    const bool bvec = ((ldb & 3) == 0) && (n0 + 128 <= N);

    f32x4 acc[4][4];
#pragma unroll
    for (int i = 0; i < 4; i++)
#pragma unroll
        for (int j = 0; j < 4; j++) acc[i][j] = (f32x4)0.f;

    for (int k0 = 0; k0 < K; k0 += 32) {
        // ---- stage A tile [128 x 32] ----
        float f[16];
        if (m0 + ar < M) {
            const float* ap = A + (size_t)(m0 + ar) * lda + (k0 + ac);
            float4 q0 = *(const float4*)(ap);
            float4 q1 = *(const float4*)(ap + 4);
            float4 q2 = *(const float4*)(ap + 8);
            float4 q3 = *(const float4*)(ap + 12);
            f[0]=q0.x; f[1]=q0.y; f[2]=q0.z; f[3]=q0.w;
            f[4]=q1.x; f[5]=q1.y; f[6]=q1.z; f[7]=q1.w;
            f[8]=q2.x; f[9]=q2.y; f[10]=q2.z; f[11]=q2.w;
            f[12]=q3.x; f[13]=q3.y; f[14]=q3.z; f[15]=q3.w;
        } else {
#pragma unroll
            for (int j = 0; j < 16; j++) f[j] = 0.f;
        }
        bf16x8 h0, h1, l0, l1;
#pragma unroll
        for (int j = 0; j < 8; j++) {
            short hh, ll;
            split_bf(f[j], hh, ll);     h0[j] = hh; l0[j] = ll;
            split_bf(f[8 + j], hh, ll); h1[j] = hh; l1[j] = ll;
        }
        // ---- load B tile [32 x 128] (2 rows x 8 cols per thread) ----
        float g0[8], g1[8];
        if (bvec) {
            const float* bp0 = B + (size_t)(k0 + kb) * ldb + (n0 + c8);
            const float* bp1 = bp0 + ldb;
            float4 q0 = *(const float4*)(bp0);
            float4 q1 = *(const float4*)(bp0 + 4);
            float4 q2 = *(const float4*)(bp1);
            float4 q3 = *(const float4*)(bp1 + 4);
            g0[0]=q0.x; g0[1]=q0.y; g0[2]=q0.z; g0[3]=q0.w;
            g0[4]=q1.x; g0[5]=q1.y; g0[6]=q1.z; g0[7]=q1.w;
            g1[0]=q2.x; g1[1]=q2.y; g1[2]=q2.z; g1[3]=q2.w;
            g1[4]=q3.x; g1[5]=q3.y; g1[6]=q3.z; g1[7]=q3.w;
        } else {
            const float* bp0 = B + (size_t)(k0 + kb) * ldb;
            const float* bp1 = bp0 + ldb;
#pragma unroll
            for (int j = 0; j < 8; j++) {
                const int nn = n0 + c8 + j;
                g0[j] = (nn < N) ? bp0[nn] : 0.f;
                g1[j] = (nn < N) ? bp1[nn] : 0.f;
            }
        }
        __syncthreads();   // previous compute done before overwrite
        *(bf16x8*)&Ah[ar * 40 + ac]     = h0;
        *(bf16x8*)&Ah[ar * 40 + ac + 8] = h1;
        *(bf16x8*)&Al[ar * 40 + ac]     = l0;
        *(bf16x8*)&Al[ar * 40 + ac + 8] = l1;
#pragma unroll
        for (int j = 0; j < 8; j++) {
            short ha, la, hb, lb;
            split_bf(g0[j], ha, la);
            split_bf(g1[j], hb, lb);
            const int ci = (c8 + j) * 40 + kb;
            *(int*)&Bh[ci] = (int)((unsigned short)ha | ((unsigned)(unsigned short)hb << 16));
            *(int*)&Bl[ci] = (int)((unsigned short)la | ((unsigned)(unsigned short)lb << 16));
        }
        __syncthreads();

        // ---- compute: 4x4 fragments of 16x16x32, 3 MFMA each ----
        bf16x8 afh[4], afl[4], bfh[4], bfl[4];
#pragma unroll
        for (int fm = 0; fm < 4; fm++) {
            const int idx = (wm + fm * 16 + lm) * 40 + lk * 8;
            afh[fm] = *(bf16x8*)&Ah[idx];
            afl[fm] = *(bf16x8*)&Al[idx];
        }
#pragma unroll
        for (int fn = 0; fn < 4; fn++) {
            const int idx = (wn + fn * 16 + lm) * 40 + lk * 8;
            bfh[fn] = *(bf16x8*)&Bh[idx];
            bfl[fn] = *(bf16x8*)&Bl[idx];
        }
#pragma unroll
        for (int fm = 0; fm < 4; fm++)
#pragma unroll
            for (int fn = 0; fn < 4; fn++) {
                acc[fm][fn] = __builtin_amdgcn_mfma_f32_16x16x32_bf16(afh[fm], bfh[fn], acc[fm][fn], 0, 0, 0);
                acc[fm][fn] = __builtin_amdgcn_mfma_f32_16x16x32_bf16(afh[fm], bfl[fn], acc[fm][fn], 0, 0, 0);
                acc[fm][fn] = __builtin_amdgcn_mfma_f32_16x16x32_bf16(afl[fm], bfh[fn], acc[fm][fn], 0, 0, 0);
            }
    }

    // ---- store ----
#pragma unroll
    for (int fm = 0; fm < 4; fm++) {
#pragma unroll
        for (int fn = 0; fn < 4; fn++) {
            const int col = n0 + wn + fn * 16 + lm;
            if (col >= N) continue;
            const float bb = bias ? bias[col] : 0.f;
#pragma unroll
            for (int r = 0; r < 4; r++) {
                const int row = m0 + wm + fm * 16 + lk * 4 + r;
                if (row >= M) continue;
                const size_t orow = pmap ? (size_t)((row & 63) * TSTEPS + (row >> 6))
                                         : (size_t)row;
                C[orow * ldc + col] = acc[fm][fn][r] + bb;
            }
        }
    }
}

// ---------------------------------------------------------------------------
// fp32 tiled GEMM (for the small per-step recurrent GEMMs), as round-2.
// ---------------------------------------------------------------------------
__global__ __launch_bounds__(256) void gemm64(
    const float* __restrict__ A, const float* __restrict__ B,
    const float* __restrict__ bias, float* __restrict__ C,
    int N, int K, int Kc, int ldc, int act, int direct)
{
    __shared__ float As[16][64];
    __shared__ float Bs[16][68];

    const int tid = threadIdx.x;
    const int n0  = blockIdx.x * 64;
    const int m0  = blockIdx.y * 64;
    const int s   = blockIdx.z;
    const int kb  = s * Kc;
    const int ke  = min(K, kb + Kc);

    const int tm = (tid >> 4) << 2;
    const int tn = (tid & 15) << 2;

    float acc[4][4];
#pragma unroll
    for (int i = 0; i < 4; i++)
#pragma unroll
        for (int j = 0; j < 4; j++) acc[i][j] = 0.f;

    const int a_m = tid >> 2;
    const int a_k = (tid & 3) << 2;
    const int b_k = tid >> 4;
    const int b_n = (tid & 15) << 2;
    const bool n4 = ((N & 3) == 0);

    for (int k0 = kb; k0 < ke; k0 += 16) {
        float4 av = *(const float4*)(A + (size_t)(m0 + a_m) * K + (k0 + a_k));
        float4 bv;
        {
            const int nn = n0 + b_n;
            const float* brow = B + (size_t)(k0 + b_k) * N;
            if (n4) {
                bv = (nn < N) ? *(const float4*)(brow + nn) : make_float4(0.f,0.f,0.f,0.f);
            } else {
                bv.x = (nn + 0 < N) ? brow[nn + 0] : 0.f;
                bv.y = (nn + 1 < N) ? brow[nn + 1] : 0.f;
                bv.z = (nn + 2 < N) ? brow[nn + 2] : 0.f;
                bv.w = (nn + 3 < N) ? brow[nn + 3] : 0.f;
            }
        }
        __syncthreads();
        As[a_k + 0][a_m] = av.x;
        As[a_k + 1][a_m] = av.y;
        As[a_k + 2][a_m] = av.z;
        As[a_k + 3][a_m] = av.w;
        *(float4*)&Bs[b_k][b_n] = bv;
        __syncthreads();
#pragma unroll
        for (int k = 0; k < 16; k++) {
            float4 a4 = *(const float4*)&As[k][tm];
            float4 b4 = *(const float4*)&Bs[k][tn];
            acc[0][0] = fmaf(a4.x, b4.x, acc[0][0]);
            acc[0][1] = fmaf(a4.x, b4.y, acc[0][1]);
            acc[0][2] = fmaf(a4.x, b4.z, acc[0][2]);
            acc[0][3] = fmaf(a4.x, b4.w, acc[0][3]);
            acc[1][0] = fmaf(a4.y, b4.x, acc[1][0]);
            acc[1][1] = fmaf(a4.y, b4.y, acc[1][1]);
            acc[1][2] = fmaf(a4.y, b4.z, acc[1][2]);
            acc[1][3] = fmaf(a4.y, b4.w, acc[1][3]);
            acc[2][0] = fmaf(a4.z, b4.x, acc[2][0]);
            acc[2][1] = fmaf(a4.z, b4.y, acc[2][1]);
            acc[2][2] = fmaf(a4.z, b4.z, acc[2][2]);
            acc[2][3] = fmaf(a4.z, b4.w, acc[2][3]);
            acc[3][0] = fmaf(a4.w, b4.x, acc[3][0]);
            acc[3][1] = fmaf(a4.w, b4.y, acc[3][1]);
            acc[3][2] = fmaf(a4.w, b4.z, acc[3][2]);
            acc[3][3] = fmaf(a4.w, b4.w, acc[3][3]);
        }
    }

    if (direct) {
#pragma unroll
        for (int i = 0; i < 4; i++) {
            const int m = m0 + tm + i;
            const size_t row = (size_t)m * ldc;
#pragma unroll
            for (int j = 0; j < 4; j++) {
                const int n = n0 + tn + j;
                if (n < N) {
                    float v = acc[i][j] + (bias ? bias[n] : 0.f);
                    if (act == 1) v = fast_tanh(v);
                    else if (act == 2) v = fast_sig(v);
                    C[row + n] = v;
                }
            }
        }
    } else {
        float* P = C + (size_t)s * 64 * N;
#pragma unroll
        for (int i = 0; i < 4; i++) {
#pragma unroll
            for (int j = 0; j < 4; j++) {
                const int n = n0 + tn + j;
                if (n < N) P[(size_t)(tm + i) * N + n] = acc[i][j];
            }
        }
    }
}

// C[m,n] = act( bias[n] + sum_s P[s][m][n] ),  m in [0,64)
__global__ __launch_bounds__(256) void reduce_partials(
    const float* __restrict__ P, int S, int N,
    const float* __restrict__ bias, float* __restrict__ C, int ldc, int act)
{
    const int idx = blockIdx.x * 256 + threadIdx.x;
    const int total = 64 * N;
    if (idx >= total) return;
    const int m = idx / N;
    const int n = idx - m * N;
    float v = bias ? bias[n] : 0.f;
    for (int s = 0; s < S; s++) v += P[(size_t)s * total + idx];
    if (act == 1) v = fast_tanh(v);
    else if (act == 2) v = fast_sig(v);
    else if (act == 3 && n >= RNND) v = fast_sig(v);
    C[(size_t)m * ldc + n] = v;
}

// gates reduce + LSTM cell fused: reads 12 P slabs (N=4096), writes h_next, c
__global__ __launch_bounds__(256) void reduce_lstm(
    const float* __restrict__ P, const float* __restrict__ bsum,
    float* __restrict__ hn, float* __restrict__ c)
{
    const int idx = blockIdx.x * 256 + threadIdx.x;   // 64*1024
    const int b = idx >> 10, r = idx & 1023;
    const float* pb = P + (size_t)b * 4096;
    float gi = bsum[r], gf = bsum[1024 + r], gg = bsum[2048 + r], go = bsum[3072 + r];
#pragma unroll 4
    for (int s = 0; s < 12; s++) {
        const float* q = pb + (size_t)s * 64 * 4096;
        gi += q[r]; gf += q[1024 + r]; gg += q[2048 + r]; go += q[3072 + r];
    }
    const float ig = fast_sig(gi);
    const float fg = fast_sig(gf);
    const float g2 = fast_tanh(gg);
    const float og = fast_sig(go);
    const float cn = fg * c[idx] + ig * g2;
    c[idx]  = cn;
    hn[idx] = og * fast_tanh(cn);
}

__global__ __launch_bounds__(256) void mean_img(
    const float* __restrict__ img, float* __restrict__ avg)
{
    const int b = blockIdx.x;
    const int d = blockIdx.y * 256 + threadIdx.x;
    const float* p = img + (size_t)b * LIMG * DIMG + d;
    float s = 0.f;
    for (int l = 0; l < LIMG; l++) s += p[(size_t)l * DIMG];
    avg[(size_t)b * DIMG + d] = s * (1.f / 196.f);
}

__global__ __launch_bounds__(256) void concat_w(
    const float* __restrict__ WU, const float* __restrict__ Wfb,
    float* __restrict__ Wug)
{
    const int idx = blockIdx.x * 256 + threadIdx.x;
    if (idx >= 1024 * 3072) return;
    const int k = idx / 3072;
    const int j = idx - k * 3072;
    Wug[idx] = (j < 1024) ? WU[(size_t)k * 1024 + j] : Wfb[(size_t)k * 2048 + (j - 1024)];
}

__global__ __launch_bounds__(256) void concat_b(
    const float* __restrict__ bU, const float* __restrict__ bfb,
    const float* __restrict__ bih, const float* __restrict__ bhh,
    float* __restrict__ bug, float* __restrict__ bsum)
{
    const int j = blockIdx.x * 256 + threadIdx.x;
    if (j < 3072) bug[j] = (j < 1024) ? bU[j] : bfb[j - 1024];
    if (j < 4096) bsum[j] = bih[j] + bhh[j];
}

// e[b,l] = tanh(Ws[b,l,:] + Uh[b,:]) . Wv + bv    (one wave per (b,l) row)
__global__ __launch_bounds__(256) void attn_e(
    const float* __restrict__ Ws, const float* __restrict__ ug,
    const float* __restrict__ Wv, const float* __restrict__ bv,
    float* __restrict__ e)
{
    const int wv   = (blockIdx.x << 2) + (threadIdx.x >> 6);
    const int lane = threadIdx.x & 63;
    const int b    = wv / LIMG;
    const float* wrow = Ws + (size_t)wv * RNND;
    const float* urow = ug + (size_t)b * 3072;
    float acc = 0.f;
#pragma unroll
    for (int k = lane * 4; k < RNND; k += 256) {
        float4 wq = *(const float4*)(wrow + k);
        float4 uq = *(const float4*)(urow + k);
        float4 vq = *(const float4*)(Wv + k);
        acc += fast_tanh(wq.x + uq.x) * vq.x + fast_tanh(wq.y + uq.y) * vq.y
             + fast_tanh(wq.z + uq.z) * vq.z + fast_tanh(wq.w + uq.w) * vq.w;
    }
#pragma unroll
    for (int off = 32; off > 0; off >>= 1) acc += __shfl_down(acc, off);
    if (lane == 0) e[wv] = acc + bv[0];
}

__global__ __launch_bounds__(256) void softmax_alpha(
    const float* __restrict__ e, float* __restrict__ alpha,
    float* __restrict__ alphas_out, int t)
{
    __shared__ float red[256];
    const int b = blockIdx.x, tid = threadIdx.x;
    const float v = (tid < LIMG) ? e[b * LIMG + tid] : -3.0e38f;
    red[tid] = v; __syncthreads();
    for (int s = 128; s > 0; s >>= 1) {
        if (tid < s) red[tid] = fmaxf(red[tid], red[tid + s]);
        __syncthreads();
    }
    const float mx = red[0]; __syncthreads();
    const float ex = (tid < LIMG) ? __expf(v - mx) : 0.f;
    red[tid] = ex; __syncthreads();
    for (int s = 128; s > 0; s >>= 1) {
        if (tid < s) red[tid] += red[tid + s];
        __syncthreads();
    }
    const float inv = 1.f / red[0];
    if (tid < LIMG) {
        const float a = ex * inv;
        alpha[b * LIMG + tid] = a;
        alphas_out[(size_t)b * (TSTEPS * LIMG) + t * LIMG + tid] = a;
    }
}

// x[b, 0:512] = emb[token], x[b, 512+d] = gate[b,d] * context[b,d]
__global__ __launch_bounds__(128) void assemble_x(
    const float* __restrict__ img, const float* __restrict__ alpha,
    const float* __restrict__ ug, const float* __restrict__ emb,
    const int* __restrict__ captions, float* __restrict__ x, int t)
{
    const int b = blockIdx.x, y = blockIdx.y, tid = threadIdx.x;
    if (y < 4) {
        const int tok = (t == 0) ? 10001 : captions[b * 16 + (t - 1)];
        const int j = y * 128 + tid;
        x[(size_t)b * 2560 + j] = emb[(size_t)tok * EMBD + j];
    } else {
        __shared__ float al[LIMG];
        for (int i = tid; i < LIMG; i += 128) al[i] = alpha[b * LIMG + i];
        __syncthreads();
        const int d = (y - 4) * 128 + tid;
        const float* ib = img + (size_t)b * LIMG * DIMG + d;
        float accv = 0.f;
#pragma unroll 4
        for (int l = 0; l < LIMG; l++) accv = fmaf(al[l], ib[(size_t)l * DIMG], accv);
        const float g = ug[(size_t)b * 3072 + 1024 + d];  // sigmoided gate
        x[(size_t)b * 2560 + EMBD + d] = g * accv;
    }
}

extern "C" void kernel_launch(void* const* d_in, const int* in_sizes, int n_in,
                              void* d_out, int out_size, void* d_ws, size_t ws_size,
                              hipStream_t stream)
{
    const float* img      = (const float*)d_in[0];
    const int*   captions = (const int*)d_in[1];
    const float* emb      = (const float*)d_in[2];
    const float* Wih      = (const float*)d_in[3];
    const float* Whh      = (const float*)d_in[4];
    const float* bih      = (const float*)d_in[5];
    const float* bhh      = (const float*)d_in[6];
    const float* Wh0      = (const float*)d_in[7];
    const float* bh0      = (const float*)d_in[8];
    const float* Wc0      = (const float*)d_in[9];
    const float* bc0      = (const float*)d_in[10];
    const float* Wfb      = (const float*)d_in[11];
    const float* bfb      = (const float*)d_in[12];
    const float* Wout     = (const float*)d_in[13];
    const float* bout     = (const float*)d_in[14];
    const float* WU       = (const float*)d_in[15];
    const float* bU       = (const float*)d_in[16];
    const float* WW       = (const float*)d_in[17];
    const float* bW       = (const float*)d_in[18];
    const float* Wv       = (const float*)d_in[19];
    const float* bv       = (const float*)d_in[20];

    float* preds      = (float*)d_out;
    float* alphas_out = preds + (size_t)NB * TSTEPS * VOUTD;

    // workspace layout (floats)
    float* w = (float*)d_ws;
    float* Ws    = w; w += (size_t)12544 * 1024;
    float* ug    = w; w += (size_t)64 * 3072;        // U_h | sigmoided gate
    float* P     = w; w += (size_t)12 * 64 * 4096;   // split-K partials
    float* e     = w; w += (size_t)64 * LIMG;
    float* alpha = w; w += (size_t)64 * LIMG;
    float* x     = w; w += (size_t)64 * 2560;
    float* Hh    = w; w += (size_t)18 * 64 * RNND;   // h history: slab 0 = h0, slab t+1 = h after step t
    float* c     = w; w += (size_t)64 * RNND;
    float* avg   = w; w += (size_t)64 * DIMG;
    float* bsum  = w; w += 4096;
    float* Wug   = w; w += (size_t)1024 * 3072;
    float* bug   = w; w += 3072;

    // ---- precompute ----
    mean_img<<<dim3(NB, 8), 256, 0, stream>>>(img, avg);

    // h0 = tanh(avg @ Wh0 + bh0) -> Hh slab 0
    gemm64<<<dim3(16, 1, 8), 256, 0, stream>>>(avg, Wh0, nullptr, P, 1024, 2048, 256, 0, 0, 0);
    reduce_partials<<<256, 256, 0, stream>>>(P, 8, 1024, bh0, Hh, 1024, 1);
    // c0 = tanh(avg @ Wc0 + bc0)
    gemm64<<<dim3(16, 1, 8), 256, 0, stream>>>(avg, Wc0, nullptr, P, 1024, 2048, 256, 0, 0, 0);
    reduce_partials<<<256, 256, 0, stream>>>(P, 8, 1024, bc0, c, 1024, 1);

    concat_b<<<16, 256, 0, stream>>>(bU, bfb, bih, bhh, bug, bsum);
    concat_w<<<12288, 256, 0, stream>>>(WU, Wfb, Wug);

    // W_s = img @ WW + bW   [12544, 1024]  via bf16x3 MFMA
    gemm_mfma3<<<dim3(8, 98), 256, 0, stream>>>(img, WW, bW, Ws,
                                                12544, 1024, 2048, 2048, 1024, 1024, 0);

    // ---- timestep loop ----
    for (int t = 0; t < TSTEPS; t++) {
        const float* h  = Hh + (size_t)t * 64 * RNND;
        float*       hn = Hh + (size_t)(t + 1) * 64 * RNND;

        // [U_h | gate] = h @ [WU | Wfb] + [bU | bfb], sigmoid on gate half
        gemm64<<<dim3(48, 1, 8), 256, 0, stream>>>(h, Wug, nullptr, P, 3072, 1024, 128, 0, 0, 0);
        reduce_partials<<<768, 256, 0, stream>>>(P, 8, 3072, bug, ug, 3072, 3);

        attn_e<<<3136, 256, 0, stream>>>(Ws, ug, Wv, bv, e);
        softmax_alpha<<<NB, 256, 0, stream>>>(e, alpha, alphas_out, t);
        assemble_x<<<dim3(NB, 20), 128, 0, stream>>>(img, alpha, ug, emb, captions, x, t);

        // gates = x @ Wih + h @ Whh + (bih+bhh); LSTM fused into reduce
        gemm64<<<dim3(64, 1, 8), 256, 0, stream>>>(x, Wih, nullptr, P, 4096, 2560, 320, 0, 0, 0);
        gemm64<<<dim3(64, 1, 4), 256, 0, stream>>>(h, Whh, nullptr, P + (size_t)8 * 64 * 4096,
                                                   4096, 1024, 256, 0, 0, 0);
        reduce_lstm<<<256, 256, 0, stream>>>(P, bsum, hn, c);
    }

    // ---- batched vocab projection: preds[b,t,:] = Hh[t+1][b] @ Wout + bout ----
    gemm_mfma3<<<dim3(79, 9), 256, 0, stream>>>(Hh + (size_t)64 * RNND, Wout, bout, preds,
                                                TSTEPS * 64, VOUTD, 1024, 1024, VOUTD, VOUTD, 1);
}

// Round 5
// 1828.115 us; speedup vs baseline: 1.9900x; 1.2913x over previous
//
#include <hip/hip_runtime.h>
#include <cstdint>

#define NB    64
#define LIMG  196
#define DIMG  2048
#define RNND  1024
#define EMBD  512
#define TSTEPS 17
#define VOUTD 10003

typedef short bf16x8 __attribute__((ext_vector_type(8)));
typedef float f32x4  __attribute__((ext_vector_type(4)));

__device__ __forceinline__ float fast_sig(float x) {
    return 1.f / (1.f + __expf(-x));
}
__device__ __forceinline__ float fast_tanh(float x) {
    float ax = fabsf(x);
    float e  = __expf(2.f * ax);
    float r  = 1.f - 2.f / (e + 1.f);
    return copysignf(r, x);
}
__device__ __forceinline__ void split_bf(float x, short& hi, short& lo) {
    unsigned u  = __float_as_uint(x);
    unsigned hb = u & 0xffff0000u;
    hi = (short)(u >> 16);
    float r = x - __uint_as_float(hb);
    lo = (short)(__float_as_uint(r) >> 16);
}

// ---------------------------------------------------------------------------
// Transpose + bf16 hi/lo split of weights:
// out[n][k] = split(in(k,n)), out row stride = K (shorts).
// nsplit>0: col n from S1 (n<nsplit, ld1) else S2 (n-nsplit, ld2).
// nsplit==0: row k from S1 (k<ksplit, ld1) else S2 (k-ksplit, ld2).
// K must be a multiple of 64. Writes only rows n < N.
// ---------------------------------------------------------------------------
__global__ __launch_bounds__(256) void tsplit(
    const float* __restrict__ S1, int ld1,
    const float* __restrict__ S2, int ld2,
    short* __restrict__ outh, short* __restrict__ outl,
    int N, int K, int ksplit, int nsplit)
{
    __shared__ float T[64][65];
    const int k0 = blockIdx.x * 64, n0 = blockIdx.y * 64;
    const int tid = threadIdx.x;
    // read phase: row rr (k-local), 16-col chunk
    const int rr = tid >> 2;
    const int cc = (tid & 3) * 16;
    const int kk = k0 + rr;
    const int nn = n0 + cc;
    const float* rp; int col;
    if (nsplit > 0) {
        if (nn >= nsplit) { rp = S2 + (size_t)kk * ld2; col = nn - nsplit; }
        else              { rp = S1 + (size_t)kk * ld1; col = nn; }
    } else {
        if (kk < ksplit)  { rp = S1 + (size_t)kk * ld1; col = nn; }
        else              { rp = S2 + (size_t)(kk - ksplit) * ld2; col = nn; }
    }
#pragma unroll
    for (int j = 0; j < 16; j++)
        T[rr][cc + j] = (nn + j < N) ? rp[col + j] : 0.f;
    __syncthreads();
    // write phase: out row gn, 16-k chunk
    const int wn = tid >> 2;
    const int wk = (tid & 3) * 16;
    const int gn = n0 + wn;
    if (gn >= N) return;
    bf16x8 h0, h1, l0, l1;
#pragma unroll
    for (int j = 0; j < 8; j++) {
        short hh, ll;
        split_bf(T[wk + j][wn], hh, ll);     h0[j] = hh; l0[j] = ll;
        split_bf(T[wk + 8 + j][wn], hh, ll); h1[j] = hh; l1[j] = ll;
    }
    const size_t o = (size_t)gn * K + k0 + wk;
    *(bf16x8*)&outh[o]     = h0;
    *(bf16x8*)&outh[o + 8] = h1;
    *(bf16x8*)&outl[o]     = l0;
    *(bf16x8*)&outl[o + 8] = l1;
}

// ---------------------------------------------------------------------------
// Big bf16x3 MFMA GEMM, B pre-split/transposed: Bh/Bl [N][K] bf16.
// A: either f32 [M,K] (Af!=null, on-the-fly split) or bf16 pair Ah16/Al16.
// Tile 128x128, BK=32, 256 threads (2x2 waves of 64x64).
// pmap=1: output row m -> (m&63)*17 + (m>>6).
// ---------------------------------------------------------------------------
__global__ __launch_bounds__(256) void gemm_bb(
    const float* __restrict__ Af,
    const short* __restrict__ Ah16, const short* __restrict__ Al16,
    const short* __restrict__ Bh16, const short* __restrict__ Bl16,
    const float* __restrict__ bias, float* __restrict__ C,
    int M, int N, int K, int lda, int ldb, int ldc, int pmap)
{
    __shared__ short Ah[128 * 40], Al[128 * 40];
    __shared__ short Bh[128 * 40], Bl[128 * 40];

    const int tid = threadIdx.x;
    const int n0  = blockIdx.x * 128;
    const int m0  = blockIdx.y * 128;

    const int lane = tid & 63;
    const int w    = tid >> 6;
    const int wm   = (w >> 1) * 64;
    const int wn   = (w & 1) * 64;
    const int lm   = lane & 15;
    const int lk   = lane >> 4;

    const int ar = tid >> 1;
    const int ac = (tid & 1) * 16;

    f32x4 acc[4][4];
#pragma unroll
    for (int i = 0; i < 4; i++)
#pragma unroll
        for (int j = 0; j < 4; j++) acc[i][j] = (f32x4)0.f;

    for (int k0 = 0; k0 < K; k0 += 32) {
        bf16x8 ah0, ah1, al0, al1;
        if (Af) {
            float f[16];
            if (m0 + ar < M) {
                const float* ap = Af + (size_t)(m0 + ar) * lda + (k0 + ac);
                float4 q0 = *(const float4*)(ap);
                float4 q1 = *(const float4*)(ap + 4);
                float4 q2 = *(const float4*)(ap + 8);
                float4 q3 = *(const float4*)(ap + 12);
                f[0]=q0.x; f[1]=q0.y; f[2]=q0.z; f[3]=q0.w;
                f[4]=q1.x; f[5]=q1.y; f[6]=q1.z; f[7]=q1.w;
                f[8]=q2.x; f[9]=q2.y; f[10]=q2.z; f[11]=q2.w;
                f[12]=q3.x; f[13]=q3.y; f[14]=q3.z; f[15]=q3.w;
            } else {
#pragma unroll
                for (int j = 0; j < 16; j++) f[j] = 0.f;
            }
#pragma unroll
            for (int j = 0; j < 8; j++) {
                short hh, ll;
                split_bf(f[j], hh, ll);     ah0[j] = hh; al0[j] = ll;
                split_bf(f[8 + j], hh, ll); ah1[j] = hh; al1[j] = ll;
            }
        } else {
            const short* p = Ah16 + (size_t)(m0 + ar) * lda + (k0 + ac);
            ah0 = *(const bf16x8*)p; ah1 = *(const bf16x8*)(p + 8);
            const short* q = Al16 + (size_t)(m0 + ar) * lda + (k0 + ac);
            al0 = *(const bf16x8*)q; al1 = *(const bf16x8*)(q + 8);
        }
        const short* pb = Bh16 + (size_t)(n0 + ar) * ldb + (k0 + ac);
        bf16x8 bh0 = *(const bf16x8*)pb, bh1 = *(const bf16x8*)(pb + 8);
        const short* qb = Bl16 + (size_t)(n0 + ar) * ldb + (k0 + ac);
        bf16x8 bl0 = *(const bf16x8*)qb, bl1 = *(const bf16x8*)(qb + 8);

        __syncthreads();
        *(bf16x8*)&Ah[ar * 40 + ac]     = ah0;
        *(bf16x8*)&Ah[ar * 40 + ac + 8] = ah1;
        *(bf16x8*)&Al[ar * 40 + ac]     = al0;
        *(bf16x8*)&Al[ar * 40 + ac + 8] = al1;
        *(bf16x8*)&Bh[ar * 40 + ac]     = bh0;
        *(bf16x8*)&Bh[ar * 40 + ac + 8] = bh1;
        *(bf16x8*)&Bl[ar * 40 + ac]     = bl0;
        *(bf16x8*)&Bl[ar * 40 + ac + 8] = bl1;
        __syncthreads();

        bf16x8 afh[4], afl[4], bfh[4], bfl[4];
#pragma unroll
        for (int fm = 0; fm < 4; fm++) {
            const int idx = (wm + fm * 16 + lm) * 40 + lk * 8;
            afh[fm] = *(bf16x8*)&Ah[idx];
            afl[fm] = *(bf16x8*)&Al[idx];
        }
#pragma unroll
        for (int fn = 0; fn < 4; fn++) {
            const int idx = (wn + fn * 16 + lm) * 40 + lk * 8;
            bfh[fn] = *(bf16x8*)&Bh[idx];
            bfl[fn] = *(bf16x8*)&Bl[idx];
        }
#pragma unroll
        for (int fm = 0; fm < 4; fm++)
#pragma unroll
            for (int fn = 0; fn < 4; fn++) {
                acc[fm][fn] = __builtin_amdgcn_mfma_f32_16x16x32_bf16(afh[fm], bfh[fn], acc[fm][fn], 0, 0, 0);
                acc[fm][fn] = __builtin_amdgcn_mfma_f32_16x16x32_bf16(afh[fm], bfl[fn], acc[fm][fn], 0, 0, 0);
                acc[fm][fn] = __builtin_amdgcn_mfma_f32_16x16x32_bf16(afl[fm], bfh[fn], acc[fm][fn], 0, 0, 0);
            }
    }

#pragma unroll
    for (int fm = 0; fm < 4; fm++) {
#pragma unroll
        for (int fn = 0; fn < 4; fn++) {
            const int col = n0 + wn + fn * 16 + lm;
            if (col >= N) continue;
            const float bb = bias ? bias[col] : 0.f;
#pragma unroll
            for (int r = 0; r < 4; r++) {
                const int row = m0 + wm + fm * 16 + lk * 4 + r;
                if (row >= M) continue;
                const size_t orow = pmap ? (size_t)((row & 63) * TSTEPS + (row >> 6))
                                         : (size_t)row;
                C[orow * ldc + col] = acc[fm][fn][r] + bb;
            }
        }
    }
}

// ---------------------------------------------------------------------------
// Skinny bf16x3 MFMA GEMM: A f32 [64,K] on-the-fly split; B pair [N][K] bf16.
// Block tile 64x128, BK=32, 4 waves (each 64x32). Split-K: z slab s covers
// K range [s*Kc, s*Kc+Kc), writes partials P + s*64*N. N multiple of 128.
// ---------------------------------------------------------------------------
__global__ __launch_bounds__(256) void gemm_sk(
    const float* __restrict__ A,
    const short* __restrict__ Bh16, const short* __restrict__ Bl16,
    float* __restrict__ P, int N, int K, int lda, int ldb, int Kc)
{
    __shared__ short Ah[64 * 40], Al[64 * 40];
    __shared__ short Bh[128 * 40], Bl[128 * 40];

    const int tid = threadIdx.x;
    const int n0  = blockIdx.x * 128;
    const int s   = blockIdx.z;
    const int kb  = s * Kc;

    const int lane = tid & 63;
    const int w    = tid >> 6;
    const int wn   = w * 32;
    const int lm   = lane & 15;
    const int lk   = lane >> 4;

    const int a_r = tid >> 2;            // 0..63
    const int a_c = (tid & 3) * 8;       // 0,8,16,24
    const int b_r = tid >> 1;            // 0..127
    const int b_c = (tid & 1) * 16;      // 0,16

    f32x4 acc[4][2];
#pragma unroll
    for (int i = 0; i < 4; i++)
#pragma unroll
        for (int j = 0; j < 2; j++) acc[i][j] = (f32x4)0.f;

    for (int k0 = kb; k0 < kb + Kc; k0 += 32) {
        const float* ap = A + (size_t)a_r * lda + (k0 + a_c);
        float4 q0 = *(const float4*)(ap);
        float4 q1 = *(const float4*)(ap + 4);
        float f[8] = {q0.x, q0.y, q0.z, q0.w, q1.x, q1.y, q1.z, q1.w};
        bf16x8 ah, al;
#pragma unroll
        for (int j = 0; j < 8; j++) {
            short hh, ll;
            split_bf(f[j], hh, ll); ah[j] = hh; al[j] = ll;
        }
        const short* pb = Bh16 + (size_t)(n0 + b_r) * ldb + (k0 + b_c);
        bf16x8 bh0 = *(const bf16x8*)pb, bh1 = *(const bf16x8*)(pb + 8);
        const short* qb = Bl16 + (size_t)(n0 + b_r) * ldb + (k0 + b_c);
        bf16x8 bl0 = *(const bf16x8*)qb, bl1 = *(const bf16x8*)(qb + 8);

        __syncthreads();
        *(bf16x8*)&Ah[a_r * 40 + a_c] = ah;
        *(bf16x8*)&Al[a_r * 40 + a_c] = al;
        *(bf16x8*)&Bh[b_r * 40 + b_c]     = bh0;
        *(bf16x8*)&Bh[b_r * 40 + b_c + 8] = bh1;
        *(bf16x8*)&Bl[b_r * 40 + b_c]     = bl0;
        *(bf16x8*)&Bl[b_r * 40 + b_c + 8] = bl1;
        __syncthreads();

        bf16x8 afh[4], afl[4], bfh[2], bfl[2];
#pragma unroll
        for (int fm = 0; fm < 4; fm++) {
            const int idx = (fm * 16 + lm) * 40 + lk * 8;
            afh[fm] = *(bf16x8*)&Ah[idx];
            afl[fm] = *(bf16x8*)&Al[idx];
        }
#pragma unroll
        for (int fn = 0; fn < 2; fn++) {
            const int idx = (wn + fn * 16 + lm) * 40 + lk * 8;
            bfh[fn] = *(bf16x8*)&Bh[idx];
            bfl[fn] = *(bf16x8*)&Bl[idx];
        }
#pragma unroll
        for (int fm = 0; fm < 4; fm++)
#pragma unroll
            for (int fn = 0; fn < 2; fn++) {
                acc[fm][fn] = __builtin_amdgcn_mfma_f32_16x16x32_bf16(afh[fm], bfh[fn], acc[fm][fn], 0, 0, 0);
                acc[fm][fn] = __builtin_amdgcn_mfma_f32_16x16x32_bf16(afh[fm], bfl[fn], acc[fm][fn], 0, 0, 0);
                acc[fm][fn] = __builtin_amdgcn_mfma_f32_16x16x32_bf16(afl[fm], bfh[fn], acc[fm][fn], 0, 0, 0);
            }
    }

    float* Ps = P + (size_t)s * 64 * N;
#pragma unroll
    for (int fm = 0; fm < 4; fm++)
#pragma unroll
        for (int fn = 0; fn < 2; fn++) {
            const int col = n0 + wn + fn * 16 + lm;
#pragma unroll
            for (int r = 0; r < 4; r++) {
                const int row = fm * 16 + lk * 4 + r;
                Ps[(size_t)row * N + col] = acc[fm][fn][r];
            }
        }
}

// ---------------------------------------------------------------------------
// fp32 tiled GEMM (h0/c0 init + fallback path)
// ---------------------------------------------------------------------------
__global__ __launch_bounds__(256) void gemm64(
    const float* __restrict__ A, const float* __restrict__ B,
    const float* __restrict__ bias, float* __restrict__ C,
    int N, int K, int Kc, int ldc, int act, int direct)
{
    __shared__ float As[16][64];
    __shared__ float Bs[16][68];

    const int tid = threadIdx.x;
    const int n0  = blockIdx.x * 64;
    const int m0  = blockIdx.y * 64;
    const int s   = blockIdx.z;
    const int kb  = s * Kc;
    const int ke  = min(K, kb + Kc);

    const int tm = (tid >> 4) << 2;
    const int tn = (tid & 15) << 2;

    float acc[4][4];
#pragma unroll
    for (int i = 0; i < 4; i++)
#pragma unroll
        for (int j = 0; j < 4; j++) acc[i][j] = 0.f;

    const int a_m = tid >> 2;
    const int a_k = (tid & 3) << 2;
    const int b_k = tid >> 4;
    const int b_n = (tid & 15) << 2;
    const bool n4 = ((N & 3) == 0);

    for (int k0 = kb; k0 < ke; k0 += 16) {
        float4 av = *(const float4*)(A + (size_t)(m0 + a_m) * K + (k0 + a_k));
        float4 bv;
        {
            const int nn = n0 + b_n;
            const float* brow = B + (size_t)(k0 + b_k) * N;
            if (n4) {
                bv = (nn < N) ? *(const float4*)(brow + nn) : make_float4(0.f,0.f,0.f,0.f);
            } else {
                bv.x = (nn + 0 < N) ? brow[nn + 0] : 0.f;
                bv.y = (nn + 1 < N) ? brow[nn + 1] : 0.f;
                bv.z = (nn + 2 < N) ? brow[nn + 2] : 0.f;
                bv.w = (nn + 3 < N) ? brow[nn + 3] : 0.f;
            }
        }
        __syncthreads();
        As[a_k + 0][a_m] = av.x;
        As[a_k + 1][a_m] = av.y;
        As[a_k + 2][a_m] = av.z;
        As[a_k + 3][a_m] = av.w;
        *(float4*)&Bs[b_k][b_n] = bv;
        __syncthreads();
#pragma unroll
        for (int k = 0; k < 16; k++) {
            float4 a4 = *(const float4*)&As[k][tm];
            float4 b4 = *(const float4*)&Bs[k][tn];
            acc[0][0] = fmaf(a4.x, b4.x, acc[0][0]);
            acc[0][1] = fmaf(a4.x, b4.y, acc[0][1]);
            acc[0][2] = fmaf(a4.x, b4.z, acc[0][2]);
            acc[0][3] = fmaf(a4.x, b4.w, acc[0][3]);
            acc[1][0] = fmaf(a4.y, b4.x, acc[1][0]);
            acc[1][1] = fmaf(a4.y, b4.y, acc[1][1]);
            acc[1][2] = fmaf(a4.y, b4.z, acc[1][2]);
            acc[1][3] = fmaf(a4.y, b4.w, acc[1][3]);
            acc[2][0] = fmaf(a4.z, b4.x, acc[2][0]);
            acc[2][1] = fmaf(a4.z, b4.y, acc[2][1]);
            acc[2][2] = fmaf(a4.z, b4.z, acc[2][2]);
            acc[2][3] = fmaf(a4.z, b4.w, acc[2][3]);
            acc[3][0] = fmaf(a4.w, b4.x, acc[3][0]);
            acc[3][1] = fmaf(a4.w, b4.y, acc[3][1]);
            acc[3][2] = fmaf(a4.w, b4.z, acc[3][2]);
            acc[3][3] = fmaf(a4.w, b4.w, acc[3][3]);
        }
    }

    if (direct) {
#pragma unroll
        for (int i = 0; i < 4; i++) {
            const int m = m0 + tm + i;
            const size_t row = (size_t)m * ldc;
#pragma unroll
            for (int j = 0; j < 4; j++) {
                const int n = n0 + tn + j;
                if (n < N) {
                    float v = acc[i][j] + (bias ? bias[n] : 0.f);
                    if (act == 1) v = fast_tanh(v);
                    else if (act == 2) v = fast_sig(v);
                    C[row + n] = v;
                }
            }
        }
    } else {
        float* Pp = C + (size_t)s * 64 * N;
#pragma unroll
        for (int i = 0; i < 4; i++) {
#pragma unroll
            for (int j = 0; j < 4; j++) {
                const int n = n0 + tn + j;
                if (n < N) Pp[(size_t)(tm + i) * N + n] = acc[i][j];
            }
        }
    }
}

// fallback big GEMM: on-the-fly split both sides (round-3, validated)
__global__ __launch_bounds__(256) void gemm_mfma3(
    const float* __restrict__ A, const float* __restrict__ B,
    const float* __restrict__ bias, float* __restrict__ C,
    int M, int N, int K, int lda, int ldb, int ldc, int pmap)
{
    __shared__ short Ah[128 * 40], Al[128 * 40];
    __shared__ short Bh[128 * 40], Bl[128 * 40];

    const int tid = threadIdx.x;
    const int n0  = blockIdx.x * 128;
    const int m0  = blockIdx.y * 128;

    const int lane = tid & 63;
    const int w    = tid >> 6;
    const int wm   = (w >> 1) * 64;
    const int wn   = (w & 1) * 64;
    const int lm   = lane & 15;
    const int lk   = lane >> 4;

    const int ar = tid >> 1;
    const int ac = (tid & 1) * 16;
    const int kb = (tid & 15) * 2;
    const int c8 = (tid >> 4) * 8;

    const bool bvec = ((ldb & 3) == 0) && (n0 + 128 <= N);

    f32x4 acc[4][4];
#pragma unroll
    for (int i = 0; i < 4; i++)
#pragma unroll
        for (int j = 0; j < 4; j++) acc[i][j] = (f32x4)0.f;

    for (int k0 = 0; k0 < K; k0 += 32) {
        float f[16];
        if (m0 + ar < M) {
            const float* ap = A + (size_t)(m0 + ar) * lda + (k0 + ac);
            float4 q0 = *(const float4*)(ap);
            float4 q1 = *(const float4*)(ap + 4);
            float4 q2 = *(const float4*)(ap + 8);
            float4 q3 = *(const float4*)(ap + 12);
            f[0]=q0.x; f[1]=q0.y; f[2]=q0.z; f[3]=q0.w;
            f[4]=q1.x; f[5]=q1.y; f[6]=q1.z; f[7]=q1.w;
            f[8]=q2.x; f[9]=q2.y; f[10]=q2.z; f[11]=q2.w;
            f[12]=q3.x; f[13]=q3.y; f[14]=q3.z; f[15]=q3.w;
        } else {
#pragma unroll
            for (int j = 0; j < 16; j++) f[j] = 0.f;
        }
        bf16x8 h0, h1, l0, l1;
#pragma unroll
        for (int j = 0; j < 8; j++) {
            short hh, ll;
            split_bf(f[j], hh, ll);     h0[j] = hh; l0[j] = ll;
            split_bf(f[8 + j], hh, ll); h1[j] = hh; l1[j] = ll;
        }
        float g0[8], g1[8];
        if (bvec) {
            const float* bp0 = B + (size_t)(k0 + kb) * ldb + (n0 + c8);
            const float* bp1 = bp0 + ldb;
            float4 q0 = *(const float4*)(bp0);
            float4 q1 = *(const float4*)(bp0 + 4);
            float4 q2 = *(const float4*)(bp1);
            float4 q3 = *(const float4*)(bp1 + 4);
            g0[0]=q0.x; g0[1]=q0.y; g0[2]=q0.z; g0[3]=q0.w;
            g0[4]=q1.x; g0[5]=q1.y; g0[6]=q1.z; g0[7]=q1.w;
            g1[0]=q2.x; g1[1]=q2.y; g1[2]=q2.z; g1[3]=q2.w;
            g1[4]=q3.x; g1[5]=q3.y; g1[6]=q3.z; g1[7]=q3.w;
        } else {
            const float* bp0 = B + (size_t)(k0 + kb) * ldb;
            const float* bp1 = bp0 + ldb;
#pragma unroll
            for (int j = 0; j < 8; j++) {
                const int nn = n0 + c8 + j;
                g0[j] = (nn < N) ? bp0[nn] : 0.f;
                g1[j] = (nn < N) ? bp1[nn] : 0.f;
            }
        }
        __syncthreads();
        *(bf16x8*)&Ah[ar * 40 + ac]     = h0;
        *(bf16x8*)&Ah[ar * 40 + ac + 8] = h1;
        *(bf16x8*)&Al[ar * 40 + ac]     = l0;
        *(bf16x8*)&Al[ar * 40 + ac + 8] = l1;
#pragma unroll
        for (int j = 0; j < 8; j++) {
            short ha, la, hb, lb;
            split_bf(g0[j], ha, la);
            split_bf(g1[j], hb, lb);
            const int ci = (c8 + j) * 40 + kb;
            *(int*)&Bh[ci] = (int)((unsigned short)ha | ((unsigned)(unsigned short)hb << 16));
            *(int*)&Bl[ci] = (int)((unsigned short)la | ((unsigned)(unsigned short)lb << 16));
        }
        __syncthreads();

        bf16x8 afh[4], afl[4], bfh[4], bfl[4];
#pragma unroll
        for (int fm = 0; fm < 4; fm++) {
            const int idx = (wm + fm * 16 + lm) * 40 + lk * 8;
            afh[fm] = *(bf16x8*)&Ah[idx];
            afl[fm] = *(bf16x8*)&Al[idx];
        }
#pragma unroll
        for (int fn = 0; fn < 4; fn++) {
            const int idx = (wn + fn * 16 + lm) * 40 + lk * 8;
            bfh[fn] = *(bf16x8*)&Bh[idx];
            bfl[fn] = *(bf16x8*)&Bl[idx];
        }
#pragma unroll
        for (int fm = 0; fm < 4; fm++)
#pragma unroll
            for (int fn = 0; fn < 4; fn++) {
                acc[fm][fn] = __builtin_amdgcn_mfma_f32_16x16x32_bf16(afh[fm], bfh[fn], acc[fm][fn], 0, 0, 0);
                acc[fm][fn] = __builtin_amdgcn_mfma_f32_16x16x32_bf16(afh[fm], bfl[fn], acc[fm][fn], 0, 0, 0);
                acc[fm][fn] = __builtin_amdgcn_mfma_f32_16x16x32_bf16(afl[fm], bfh[fn], acc[fm][fn], 0, 0, 0);
            }
    }

#pragma unroll
    for (int fm = 0; fm < 4; fm++) {
#pragma unroll
        for (int fn = 0; fn < 4; fn++) {
            const int col = n0 + wn + fn * 16 + lm;
            if (col >= N) continue;
            const float bb = bias ? bias[col] : 0.f;
#pragma unroll
            for (int r = 0; r < 4; r++) {
                const int row = m0 + wm + fm * 16 + lk * 4 + r;
                if (row >= M) continue;
                const size_t orow = pmap ? (size_t)((row & 63) * TSTEPS + (row >> 6))
                                         : (size_t)row;
                C[orow * ldc + col] = acc[fm][fn][r] + bb;
            }
        }
    }
}

__global__ __launch_bounds__(256) void reduce_partials(
    const float* __restrict__ P, int S, int N,
    const float* __restrict__ bias, float* __restrict__ C, int ldc, int act)
{
    const int idx = blockIdx.x * 256 + threadIdx.x;
    const int total = 64 * N;
    if (idx >= total) return;
    const int m = idx / N;
    const int n = idx - m * N;
    float v = bias ? bias[n] : 0.f;
    for (int s = 0; s < S; s++) v += P[(size_t)s * total + idx];
    if (act == 1) v = fast_tanh(v);
    else if (act == 2) v = fast_sig(v);
    else if (act == 3 && n >= RNND) v = fast_sig(v);
    C[(size_t)m * ldc + n] = v;
}

// gates reduce + LSTM cell fused; optional bf16 h output (hi/lo)
__global__ __launch_bounds__(256) void reduce_lstm(
    const float* __restrict__ P, int S, const float* __restrict__ bsum,
    float* __restrict__ hn, float* __restrict__ c,
    short* __restrict__ hbh, short* __restrict__ hbl)
{
    const int idx = blockIdx.x * 256 + threadIdx.x;   // 64*1024
    const int b = idx >> 10, r = idx & 1023;
    const float* pb = P + (size_t)b * 4096;
    float gi = bsum[r], gf = bsum[1024 + r], gg = bsum[2048 + r], go = bsum[3072 + r];
    for (int s = 0; s < S; s++) {
        const float* q = pb + (size_t)s * 64 * 4096;
        gi += q[r]; gf += q[1024 + r]; gg += q[2048 + r]; go += q[3072 + r];
    }
    const float ig = fast_sig(gi);
    const float fg = fast_sig(gf);
    const float g2 = fast_tanh(gg);
    const float og = fast_sig(go);
    const float cn = fg * c[idx] + ig * g2;
    const float hv = og * fast_tanh(cn);
    c[idx]  = cn;
    hn[idx] = hv;
    if (hbh) {
        short hi, lo;
        split_bf(hv, hi, lo);
        hbh[idx] = hi;
        hbl[idx] = lo;
    }
}

__global__ __launch_bounds__(256) void mean_img(
    const float* __restrict__ img, float* __restrict__ avg)
{
    const int b = blockIdx.x;
    const int d = blockIdx.y * 256 + threadIdx.x;
    const float* p = img + (size_t)b * LIMG * DIMG + d;
    float s = 0.f;
    for (int l = 0; l < LIMG; l++) s += p[(size_t)l * DIMG];
    avg[(size_t)b * DIMG + d] = s * (1.f / 196.f);
}

__global__ __launch_bounds__(256) void concat_w(
    const float* __restrict__ WU, const float* __restrict__ Wfb,
    float* __restrict__ Wug)
{
    const int idx = blockIdx.x * 256 + threadIdx.x;
    if (idx >= 1024 * 3072) return;
    const int k = idx / 3072;
    const int j = idx - k * 3072;
    Wug[idx] = (j < 1024) ? WU[(size_t)k * 1024 + j] : Wfb[(size_t)k * 2048 + (j - 1024)];
}

__global__ __launch_bounds__(256) void concat_b(
    const float* __restrict__ bU, const float* __restrict__ bfb,
    const float* __restrict__ bih, const float* __restrict__ bhh,
    float* __restrict__ bug, float* __restrict__ bsum)
{
    const int j = blockIdx.x * 256 + threadIdx.x;
    if (j < 3072) bug[j] = (j < 1024) ? bU[j] : bfb[j - 1024];
    if (j < 4096) bsum[j] = bih[j] + bhh[j];
}

__global__ __launch_bounds__(256) void attn_e(
    const float* __restrict__ Ws, const float* __restrict__ ug,
    const float* __restrict__ Wv, const float* __restrict__ bv,
    float* __restrict__ e)
{
    const int wv   = (blockIdx.x << 2) + (threadIdx.x >> 6);
    const int lane = threadIdx.x & 63;
    const int b    = wv / LIMG;
    const float* wrow = Ws + (size_t)wv * RNND;
    const float* urow = ug + (size_t)b * 3072;
    float acc = 0.f;
#pragma unroll
    for (int k = lane * 4; k < RNND; k += 256) {
        float4 wq = *(const float4*)(wrow + k);
        float4 uq = *(const float4*)(urow + k);
        float4 vq = *(const float4*)(Wv + k);
        acc += fast_tanh(wq.x + uq.x) * vq.x + fast_tanh(wq.y + uq.y) * vq.y
             + fast_tanh(wq.z + uq.z) * vq.z + fast_tanh(wq.w + uq.w) * vq.w;
    }
#pragma unroll
    for (int off = 32; off > 0; off >>= 1) acc += __shfl_down(acc, off);
    if (lane == 0) e[wv] = acc + bv[0];
}

__global__ __launch_bounds__(256) void softmax_alpha(
    const float* __restrict__ e, float* __restrict__ alpha,
    float* __restrict__ alphas_out, int t)
{
    __shared__ float red[256];
    const int b = blockIdx.x, tid = threadIdx.x;
    const float v = (tid < LIMG) ? e[b * LIMG + tid] : -3.0e38f;
    red[tid] = v; __syncthreads();
    for (int s = 128; s > 0; s >>= 1) {
        if (tid < s) red[tid] = fmaxf(red[tid], red[tid + s]);
        __syncthreads();
    }
    const float mx = red[0]; __syncthreads();
    const float ex = (tid < LIMG) ? __expf(v - mx) : 0.f;
    red[tid] = ex; __syncthreads();
    for (int s = 128; s > 0; s >>= 1) {
        if (tid < s) red[tid] += red[tid + s];
        __syncthreads();
    }
    const float inv = 1.f / red[0];
    if (tid < LIMG) {
        const float a = ex * inv;
        alpha[b * LIMG + tid] = a;
        alphas_out[(size_t)b * (TSTEPS * LIMG) + t * LIMG + tid] = a;
    }
}

// y<4: emb -> x[0:512]; y in [4,20): gate*ctx -> x[512+d]; y>=20: h -> x[2560+j]
__global__ __launch_bounds__(128) void assemble_x(
    const float* __restrict__ img, const float* __restrict__ alpha,
    const float* __restrict__ ug, const float* __restrict__ emb,
    const int* __restrict__ captions, const float* __restrict__ h,
    float* __restrict__ x, int t, int stride)
{
    const int b = blockIdx.x, y = blockIdx.y, tid = threadIdx.x;
    if (y < 4) {
        const int tok = (t == 0) ? 10001 : captions[b * 16 + (t - 1)];
        const int j = y * 128 + tid;
        x[(size_t)b * stride + j] = emb[(size_t)tok * EMBD + j];
    } else if (y < 20) {
        __shared__ float al[LIMG];
        for (int i = tid; i < LIMG; i += 128) al[i] = alpha[b * LIMG + i];
        __syncthreads();
        const int d = (y - 4) * 128 + tid;
        const float* ib = img + (size_t)b * LIMG * DIMG + d;
        float accv = 0.f;
#pragma unroll 4
        for (int l = 0; l < LIMG; l++) accv = fmaf(al[l], ib[(size_t)l * DIMG], accv);
        const float g = ug[(size_t)b * 3072 + 1024 + d];
        x[(size_t)b * stride + EMBD + d] = g * accv;
    } else {
        const int j = (y - 20) * 128 + tid;
        x[(size_t)b * stride + 2560 + j] = h[(size_t)b * RNND + j];
    }
}

extern "C" void kernel_launch(void* const* d_in, const int* in_sizes, int n_in,
                              void* d_out, int out_size, void* d_ws, size_t ws_size,
                              hipStream_t stream)
{
    const float* img      = (const float*)d_in[0];
    const int*   captions = (const int*)d_in[1];
    const float* emb      = (const float*)d_in[2];
    const float* Wih      = (const float*)d_in[3];
    const float* Whh      = (const float*)d_in[4];
    const float* bih      = (const float*)d_in[5];
    const float* bhh      = (const float*)d_in[6];
    const float* Wh0      = (const float*)d_in[7];
    const float* bh0      = (const float*)d_in[8];
    const float* Wc0      = (const float*)d_in[9];
    const float* bc0      = (const float*)d_in[10];
    const float* Wfb      = (const float*)d_in[11];
    const float* bfb      = (const float*)d_in[12];
    const float* Wout     = (const float*)d_in[13];
    const float* bout     = (const float*)d_in[14];
    const float* WU       = (const float*)d_in[15];
    const float* bU       = (const float*)d_in[16];
    const float* WW       = (const float*)d_in[17];
    const float* bW       = (const float*)d_in[18];
    const float* Wv       = (const float*)d_in[19];
    const float* bv       = (const float*)d_in[20];

    float* preds      = (float*)d_out;
    float* alphas_out = preds + (size_t)NB * TSTEPS * VOUTD;

    const size_t NEED = 190000000;   // new-path ws bytes (~189.0 MB used)

    if (ws_size >= NEED) {
        // ---------------- new path: pre-split weights, MFMA everywhere ----------------
        float* w = (float*)d_ws;
        float* Ws    = w; w += (size_t)12544 * 1024;
        float* ug    = w; w += (size_t)64 * 3072;
        float* P     = w; w += (size_t)8 * 64 * 4096;
        float* e     = w; w += (size_t)64 * LIMG;
        float* alpha = w; w += (size_t)64 * LIMG;
        float* xh    = w; w += (size_t)64 * 3584;
        float* h     = w; w += (size_t)64 * RNND;
        float* c     = w; w += (size_t)64 * RNND;
        float* avg   = w; w += (size_t)64 * DIMG;
        float* bsum  = w; w += 4096;
        float* bug   = w; w += 3072;
        short* u = (short*)w;
        short* Hbh     = u; u += (size_t)1280 * 1024;
        short* Hbl     = u; u += (size_t)1280 * 1024;
        short* WWTh    = u; u += (size_t)1024 * 2048;
        short* WWTl    = u; u += (size_t)1024 * 2048;
        short* WugTh   = u; u += (size_t)3072 * 1024;
        short* WugTl   = u; u += (size_t)3072 * 1024;
        short* WfullTh = u; u += (size_t)4096 * 3584;
        short* WfullTl = u; u += (size_t)4096 * 3584;
        short* WoutTh  = u; u += (size_t)10112 * 1024;
        short* WoutTl  = u; u += (size_t)10112 * 1024;

        mean_img<<<dim3(NB, 8), 256, 0, stream>>>(img, avg);
        gemm64<<<dim3(16, 1, 8), 256, 0, stream>>>(avg, Wh0, nullptr, P, 1024, 2048, 256, 0, 0, 0);
        reduce_partials<<<256, 256, 0, stream>>>(P, 8, 1024, bh0, h, 1024, 1);
        gemm64<<<dim3(16, 1, 8), 256, 0, stream>>>(avg, Wc0, nullptr, P, 1024, 2048, 256, 0, 0, 0);
        reduce_partials<<<256, 256, 0, stream>>>(P, 8, 1024, bc0, c, 1024, 1);
        concat_b<<<16, 256, 0, stream>>>(bU, bfb, bih, bhh, bug, bsum);

        tsplit<<<dim3(32, 16), 256, 0, stream>>>(WW, 1024, WW, 1024, WWTh, WWTl, 1024, 2048, 2048, 0);
        tsplit<<<dim3(16, 48), 256, 0, stream>>>(WU, 1024, Wfb, 2048, WugTh, WugTl, 3072, 1024, 1024, 1024);
        tsplit<<<dim3(56, 64), 256, 0, stream>>>(Wih, 4096, Whh, 4096, WfullTh, WfullTl, 4096, 3584, 2560, 0);
        tsplit<<<dim3(16, 157), 256, 0, stream>>>(Wout, VOUTD, Wout, VOUTD, WoutTh, WoutTl, VOUTD, 1024, 1024, 0);

        // W_s = img @ WW + bW
        gemm_bb<<<dim3(8, 98), 256, 0, stream>>>(img, nullptr, nullptr, WWTh, WWTl,
                                                 bW, Ws, 12544, 1024, 2048, 2048, 2048, 1024, 0);

        for (int t = 0; t < TSTEPS; t++) {
            gemm_sk<<<dim3(24, 1, 8), 256, 0, stream>>>(h, WugTh, WugTl, P, 3072, 1024, 1024, 1024, 128);
            reduce_partials<<<768, 256, 0, stream>>>(P, 8, 3072, bug, ug, 3072, 3);
            attn_e<<<3136, 256, 0, stream>>>(Ws, ug, Wv, bv, e);
            softmax_alpha<<<NB, 256, 0, stream>>>(e, alpha, alphas_out, t);
            assemble_x<<<dim3(NB, 28), 128, 0, stream>>>(img, alpha, ug, emb, captions, h, xh, t, 3584);
            gemm_sk<<<dim3(32, 1, 7), 256, 0, stream>>>(xh, WfullTh, WfullTl, P, 4096, 3584, 3584, 3584, 512);
            reduce_lstm<<<256, 256, 0, stream>>>(P, 7, bsum, h, c,
                                                 Hbh + (size_t)(t + 1) * 65536,
                                                 Hbl + (size_t)(t + 1) * 65536);
        }

        // preds[b,t,:] = h_t @ Wout + bout  (A = Hbf slabs 1..17, bf16 pair)
        gemm_bb<<<dim3(79, 9), 256, 0, stream>>>(nullptr, Hbh + 65536, Hbl + 65536,
                                                 WoutTh, WoutTl, bout, preds,
                                                 1088, VOUTD, 1024, 1024, 1024, VOUTD, 1);
    } else {
        // ---------------- fallback: round-3 sequence (ws ~83 MB) ----------------
        float* w = (float*)d_ws;
        float* Ws    = w; w += (size_t)12544 * 1024;
        float* ug    = w; w += (size_t)64 * 3072;
        float* P     = w; w += (size_t)12 * 64 * 4096;
        float* e     = w; w += (size_t)64 * LIMG;
        float* alpha = w; w += (size_t)64 * LIMG;
        float* x     = w; w += (size_t)64 * 2560;
        float* Hh    = w; w += (size_t)18 * 64 * RNND;
        float* c     = w; w += (size_t)64 * RNND;
        float* avg   = w; w += (size_t)64 * DIMG;
        float* bsum  = w; w += 4096;
        float* Wug   = w; w += (size_t)1024 * 3072;
        float* bug   = w; w += 3072;

        mean_img<<<dim3(NB, 8), 256, 0, stream>>>(img, avg);
        gemm64<<<dim3(16, 1, 8), 256, 0, stream>>>(avg, Wh0, nullptr, P, 1024, 2048, 256, 0, 0, 0);
        reduce_partials<<<256, 256, 0, stream>>>(P, 8, 1024, bh0, Hh, 1024, 1);
        gemm64<<<dim3(16, 1, 8), 256, 0, stream>>>(avg, Wc0, nullptr, P, 1024, 2048, 256, 0, 0, 0);
        reduce_partials<<<256, 256, 0, stream>>>(P, 8, 1024, bc0, c, 1024, 1);
        concat_b<<<16, 256, 0, stream>>>(bU, bfb, bih, bhh, bug, bsum);
        concat_w<<<12288, 256, 0, stream>>>(WU, Wfb, Wug);
        gemm_mfma3<<<dim3(8, 98), 256, 0, stream>>>(img, WW, bW, Ws,
                                                    12544, 1024, 2048, 2048, 1024, 1024, 0);
        for (int t = 0; t < TSTEPS; t++) {
            const float* h  = Hh + (size_t)t * 64 * RNND;
            float*       hn = Hh + (size_t)(t + 1) * 64 * RNND;
            gemm64<<<dim3(48, 1, 8), 256, 0, stream>>>(h, Wug, nullptr, P, 3072, 1024, 128, 0, 0, 0);
            reduce_partials<<<768, 256, 0, stream>>>(P, 8, 3072, bug, ug, 3072, 3);
            attn_e<<<3136, 256, 0, stream>>>(Ws, ug, Wv, bv, e);
            softmax_alpha<<<NB, 256, 0, stream>>>(e, alpha, alphas_out, t);
            assemble_x<<<dim3(NB, 20), 128, 0, stream>>>(img, alpha, ug, emb, captions, h, x, t, 2560);
            gemm64<<<dim3(64, 1, 8), 256, 0, stream>>>(x, Wih, nullptr, P, 4096, 2560, 320, 0, 0, 0);
            gemm64<<<dim3(64, 1, 4), 256, 0, stream>>>(h, Whh, nullptr, P + (size_t)8 * 64 * 4096,
                                                       4096, 1024, 256, 0, 0, 0);
            reduce_lstm<<<256, 256, 0, stream>>>(P, 12, bsum, hn, c, nullptr, nullptr);
        }
        gemm_mfma3<<<dim3(79, 9), 256, 0, stream>>>(Hh + (size_t)64 * RNND, Wout, bout, preds,
                                                    TSTEPS * 64, VOUTD, 1024, 1024, VOUTD, VOUTD, 1);
    }
}

// Round 6
// 1769.122 us; speedup vs baseline: 2.0563x; 1.0333x over previous
//
#include <hip/hip_runtime.h>
#include <cstdint>

#define NB    64
#define LIMG  196
#define DIMG  2048
#define RNND  1024
#define EMBD  512
#define TSTEPS 17
#define VOUTD 10003

typedef short bf16x8 __attribute__((ext_vector_type(8)));
typedef float f32x4  __attribute__((ext_vector_type(4)));

__device__ __forceinline__ float fast_sig(float x) {
    return 1.f / (1.f + __expf(-x));
}
__device__ __forceinline__ float fast_tanh(float x) {
    float ax = fabsf(x);
    float e  = __expf(2.f * ax);
    float r  = 1.f - 2.f / (e + 1.f);
    return copysignf(r, x);
}
__device__ __forceinline__ void split_bf(float x, short& hi, short& lo) {
    unsigned u  = __float_as_uint(x);
    unsigned hb = u & 0xffff0000u;
    hi = (short)(u >> 16);
    float r = x - __uint_as_float(hb);
    lo = (short)(__float_as_uint(r) >> 16);
}

// ---------------------------------------------------------------------------
// Transpose + bf16 hi/lo split of weights (unchanged from round 4/5)
// ---------------------------------------------------------------------------
__global__ __launch_bounds__(256) void tsplit(
    const float* __restrict__ S1, int ld1,
    const float* __restrict__ S2, int ld2,
    short* __restrict__ outh, short* __restrict__ outl,
    int N, int K, int ksplit, int nsplit)
{
    __shared__ float T[64][65];
    const int k0 = blockIdx.x * 64, n0 = blockIdx.y * 64;
    const int tid = threadIdx.x;
    const int rr = tid >> 2;
    const int cc = (tid & 3) * 16;
    const int kk = k0 + rr;
    const int nn = n0 + cc;
    const float* rp; int col;
    if (nsplit > 0) {
        if (nn >= nsplit) { rp = S2 + (size_t)kk * ld2; col = nn - nsplit; }
        else              { rp = S1 + (size_t)kk * ld1; col = nn; }
    } else {
        if (kk < ksplit)  { rp = S1 + (size_t)kk * ld1; col = nn; }
        else              { rp = S2 + (size_t)(kk - ksplit) * ld2; col = nn; }
    }
#pragma unroll
    for (int j = 0; j < 16; j++)
        T[rr][cc + j] = (nn + j < N) ? rp[col + j] : 0.f;
    __syncthreads();
    const int wn = tid >> 2;
    const int wk = (tid & 3) * 16;
    const int gn = n0 + wn;
    if (gn >= N) return;
    bf16x8 h0, h1, l0, l1;
#pragma unroll
    for (int j = 0; j < 8; j++) {
        short hh, ll;
        split_bf(T[wk + j][wn], hh, ll);     h0[j] = hh; l0[j] = ll;
        split_bf(T[wk + 8 + j][wn], hh, ll); h1[j] = hh; l1[j] = ll;
    }
    const size_t o = (size_t)gn * K + k0 + wk;
    *(bf16x8*)&outh[o]     = h0;
    *(bf16x8*)&outh[o + 8] = h1;
    *(bf16x8*)&outl[o]     = l0;
    *(bf16x8*)&outl[o + 8] = l1;
}

// ---------------------------------------------------------------------------
// Big bf16x3 MFMA GEMM with XCD-aware work remap.
// 1-D grid, padded: grid.x = 8 * ceil(G/8) * O where G = group-axis tiles,
// O = other-axis tiles. gax=1: group by m (y); gax=0: group by n (x).
// Blocks sharing the group-axis value run on consecutive slots of ONE XCD
// (bid%8 heuristic) -> shared operand panel stays in that XCD's L2.
// ---------------------------------------------------------------------------
__global__ __launch_bounds__(256) void gemm_bb(
    const float* __restrict__ Af,
    const short* __restrict__ Ah16, const short* __restrict__ Al16,
    const short* __restrict__ Bh16, const short* __restrict__ Bl16,
    const float* __restrict__ bias, float* __restrict__ C,
    int M, int N, int K, int lda, int ldb, int ldc, int pmap,
    int nx, int ny, int gax)
{
    __shared__ short Ah[128 * 40], Al[128 * 40];
    __shared__ short Bh[128 * 40], Bl[128 * 40];

    const int p    = blockIdx.x;
    const int xcd  = p & 7;
    const int slot = p >> 3;
    const int G = gax ? ny : nx;
    const int O = gax ? nx : ny;
    const int qb = G >> 3, qr = G & 7;
    const int cnt = qb + (xcd < qr ? 1 : 0);
    if (slot >= cnt * O) return;
    const int start = xcd * qb + min(xcd, qr);
    const int g = start + slot / O;
    const int o = slot - (slot / O) * O;
    const int n0 = (gax ? o : g) * 128;
    const int m0 = (gax ? g : o) * 128;

    const int tid = threadIdx.x;
    const int lane = tid & 63;
    const int w    = tid >> 6;
    const int wm   = (w >> 1) * 64;
    const int wn   = (w & 1) * 64;
    const int lm   = lane & 15;
    const int lk   = lane >> 4;

    const int ar = tid >> 1;
    const int ac = (tid & 1) * 16;

    f32x4 acc[4][4];
#pragma unroll
    for (int i = 0; i < 4; i++)
#pragma unroll
        for (int j = 0; j < 4; j++) acc[i][j] = (f32x4)0.f;

    for (int k0 = 0; k0 < K; k0 += 32) {
        bf16x8 ah0, ah1, al0, al1;
        if (Af) {
            float f[16];
            if (m0 + ar < M) {
                const float* ap = Af + (size_t)(m0 + ar) * lda + (k0 + ac);
                float4 q0 = *(const float4*)(ap);
                float4 q1 = *(const float4*)(ap + 4);
                float4 q2 = *(const float4*)(ap + 8);
                float4 q3 = *(const float4*)(ap + 12);
                f[0]=q0.x; f[1]=q0.y; f[2]=q0.z; f[3]=q0.w;
                f[4]=q1.x; f[5]=q1.y; f[6]=q1.z; f[7]=q1.w;
                f[8]=q2.x; f[9]=q2.y; f[10]=q2.z; f[11]=q2.w;
                f[12]=q3.x; f[13]=q3.y; f[14]=q3.z; f[15]=q3.w;
            } else {
#pragma unroll
                for (int j = 0; j < 16; j++) f[j] = 0.f;
            }
#pragma unroll
            for (int j = 0; j < 8; j++) {
                short hh, ll;
                split_bf(f[j], hh, ll);     ah0[j] = hh; al0[j] = ll;
                split_bf(f[8 + j], hh, ll); ah1[j] = hh; al1[j] = ll;
            }
        } else {
            const short* pa = Ah16 + (size_t)(m0 + ar) * lda + (k0 + ac);
            ah0 = *(const bf16x8*)pa; ah1 = *(const bf16x8*)(pa + 8);
            const short* qa = Al16 + (size_t)(m0 + ar) * lda + (k0 + ac);
            al0 = *(const bf16x8*)qa; al1 = *(const bf16x8*)(qa + 8);
        }
        const short* pb = Bh16 + (size_t)(n0 + ar) * ldb + (k0 + ac);
        bf16x8 bh0 = *(const bf16x8*)pb, bh1 = *(const bf16x8*)(pb + 8);
        const short* qb2 = Bl16 + (size_t)(n0 + ar) * ldb + (k0 + ac);
        bf16x8 bl0 = *(const bf16x8*)qb2, bl1 = *(const bf16x8*)(qb2 + 8);

        __syncthreads();
        *(bf16x8*)&Ah[ar * 40 + ac]     = ah0;
        *(bf16x8*)&Ah[ar * 40 + ac + 8] = ah1;
        *(bf16x8*)&Al[ar * 40 + ac]     = al0;
        *(bf16x8*)&Al[ar * 40 + ac + 8] = al1;
        *(bf16x8*)&Bh[ar * 40 + ac]     = bh0;
        *(bf16x8*)&Bh[ar * 40 + ac + 8] = bh1;
        *(bf16x8*)&Bl[ar * 40 + ac]     = bl0;
        *(bf16x8*)&Bl[ar * 40 + ac + 8] = bl1;
        __syncthreads();

        bf16x8 afh[4], afl[4], bfh[4], bfl[4];
#pragma unroll
        for (int fm = 0; fm < 4; fm++) {
            const int idx = (wm + fm * 16 + lm) * 40 + lk * 8;
            afh[fm] = *(bf16x8*)&Ah[idx];
            afl[fm] = *(bf16x8*)&Al[idx];
        }
#pragma unroll
        for (int fn = 0; fn < 4; fn++) {
            const int idx = (wn + fn * 16 + lm) * 40 + lk * 8;
            bfh[fn] = *(bf16x8*)&Bh[idx];
            bfl[fn] = *(bf16x8*)&Bl[idx];
        }
#pragma unroll
        for (int fm = 0; fm < 4; fm++)
#pragma unroll
            for (int fn = 0; fn < 4; fn++) {
                acc[fm][fn] = __builtin_amdgcn_mfma_f32_16x16x32_bf16(afh[fm], bfh[fn], acc[fm][fn], 0, 0, 0);
                acc[fm][fn] = __builtin_amdgcn_mfma_f32_16x16x32_bf16(afh[fm], bfl[fn], acc[fm][fn], 0, 0, 0);
                acc[fm][fn] = __builtin_amdgcn_mfma_f32_16x16x32_bf16(afl[fm], bfh[fn], acc[fm][fn], 0, 0, 0);
            }
    }

#pragma unroll
    for (int fm = 0; fm < 4; fm++) {
#pragma unroll
        for (int fn = 0; fn < 4; fn++) {
            const int col = n0 + wn + fn * 16 + lm;
            if (col >= N) continue;
            const float bb = bias ? bias[col] : 0.f;
#pragma unroll
            for (int r = 0; r < 4; r++) {
                const int row = m0 + wm + fm * 16 + lk * 4 + r;
                if (row >= M) continue;
                const size_t orow = pmap ? (size_t)((row & 63) * TSTEPS + (row >> 6))
                                         : (size_t)row;
                C[orow * ldc + col] = acc[fm][fn][r] + bb;
            }
        }
    }
}

// ---------------------------------------------------------------------------
// Skinny bf16x3 MFMA GEMM (unchanged)
// ---------------------------------------------------------------------------
__global__ __launch_bounds__(256) void gemm_sk(
    const float* __restrict__ A,
    const short* __restrict__ Bh16, const short* __restrict__ Bl16,
    float* __restrict__ P, int N, int K, int lda, int ldb, int Kc)
{
    __shared__ short Ah[64 * 40], Al[64 * 40];
    __shared__ short Bh[128 * 40], Bl[128 * 40];

    const int tid = threadIdx.x;
    const int n0  = blockIdx.x * 128;
    const int s   = blockIdx.z;
    const int kb  = s * Kc;

    const int lane = tid & 63;
    const int w    = tid >> 6;
    const int wn   = w * 32;
    const int lm   = lane & 15;
    const int lk   = lane >> 4;

    const int a_r = tid >> 2;
    const int a_c = (tid & 3) * 8;
    const int b_r = tid >> 1;
    const int b_c = (tid & 1) * 16;

    f32x4 acc[4][2];
#pragma unroll
    for (int i = 0; i < 4; i++)
#pragma unroll
        for (int j = 0; j < 2; j++) acc[i][j] = (f32x4)0.f;

    for (int k0 = kb; k0 < kb + Kc; k0 += 32) {
        const float* ap = A + (size_t)a_r * lda + (k0 + a_c);
        float4 q0 = *(const float4*)(ap);
        float4 q1 = *(const float4*)(ap + 4);
        float f[8] = {q0.x, q0.y, q0.z, q0.w, q1.x, q1.y, q1.z, q1.w};
        bf16x8 ah, al;
#pragma unroll
        for (int j = 0; j < 8; j++) {
            short hh, ll;
            split_bf(f[j], hh, ll); ah[j] = hh; al[j] = ll;
        }
        const short* pb = Bh16 + (size_t)(n0 + b_r) * ldb + (k0 + b_c);
        bf16x8 bh0 = *(const bf16x8*)pb, bh1 = *(const bf16x8*)(pb + 8);
        const short* qb = Bl16 + (size_t)(n0 + b_r) * ldb + (k0 + b_c);
        bf16x8 bl0 = *(const bf16x8*)qb, bl1 = *(const bf16x8*)(qb + 8);

        __syncthreads();
        *(bf16x8*)&Ah[a_r * 40 + a_c] = ah;
        *(bf16x8*)&Al[a_r * 40 + a_c] = al;
        *(bf16x8*)&Bh[b_r * 40 + b_c]     = bh0;
        *(bf16x8*)&Bh[b_r * 40 + b_c + 8] = bh1;
        *(bf16x8*)&Bl[b_r * 40 + b_c]     = bl0;
        *(bf16x8*)&Bl[b_r * 40 + b_c + 8] = bl1;
        __syncthreads();

        bf16x8 afh[4], afl[4], bfh[2], bfl[2];
#pragma unroll
        for (int fm = 0; fm < 4; fm++) {
            const int idx = (fm * 16 + lm) * 40 + lk * 8;
            afh[fm] = *(bf16x8*)&Ah[idx];
            afl[fm] = *(bf16x8*)&Al[idx];
        }
#pragma unroll
        for (int fn = 0; fn < 2; fn++) {
            const int idx = (wn + fn * 16 + lm) * 40 + lk * 8;
            bfh[fn] = *(bf16x8*)&Bh[idx];
            bfl[fn] = *(bf16x8*)&Bl[idx];
        }
#pragma unroll
        for (int fm = 0; fm < 4; fm++)
#pragma unroll
            for (int fn = 0; fn < 2; fn++) {
                acc[fm][fn] = __builtin_amdgcn_mfma_f32_16x16x32_bf16(afh[fm], bfh[fn], acc[fm][fn], 0, 0, 0);
                acc[fm][fn] = __builtin_amdgcn_mfma_f32_16x16x32_bf16(afh[fm], bfl[fn], acc[fm][fn], 0, 0, 0);
                acc[fm][fn] = __builtin_amdgcn_mfma_f32_16x16x32_bf16(afl[fm], bfh[fn], acc[fm][fn], 0, 0, 0);
            }
    }

    float* Ps = P + (size_t)s * 64 * N;
#pragma unroll
    for (int fm = 0; fm < 4; fm++)
#pragma unroll
        for (int fn = 0; fn < 2; fn++) {
            const int col = n0 + wn + fn * 16 + lm;
#pragma unroll
            for (int r = 0; r < 4; r++) {
                const int row = fm * 16 + lk * 4 + r;
                Ps[(size_t)row * N + col] = acc[fm][fn][r];
            }
        }
}

// ---------------------------------------------------------------------------
// fp32 tiled GEMM (h0/c0 init + fallback)
// ---------------------------------------------------------------------------
__global__ __launch_bounds__(256) void gemm64(
    const float* __restrict__ A, const float* __restrict__ B,
    const float* __restrict__ bias, float* __restrict__ C,
    int N, int K, int Kc, int ldc, int act, int direct)
{
    __shared__ float As[16][64];
    __shared__ float Bs[16][68];

    const int tid = threadIdx.x;
    const int n0  = blockIdx.x * 64;
    const int m0  = blockIdx.y * 64;
    const int s   = blockIdx.z;
    const int kb  = s * Kc;
    const int ke  = min(K, kb + Kc);

    const int tm = (tid >> 4) << 2;
    const int tn = (tid & 15) << 2;

    float acc[4][4];
#pragma unroll
    for (int i = 0; i < 4; i++)
#pragma unroll
        for (int j = 0; j < 4; j++) acc[i][j] = 0.f;

    const int a_m = tid >> 2;
    const int a_k = (tid & 3) << 2;
    const int b_k = tid >> 4;
    const int b_n = (tid & 15) << 2;
    const bool n4 = ((N & 3) == 0);

    for (int k0 = kb; k0 < ke; k0 += 16) {
        float4 av = *(const float4*)(A + (size_t)(m0 + a_m) * K + (k0 + a_k));
        float4 bv;
        {
            const int nn = n0 + b_n;
            const float* brow = B + (size_t)(k0 + b_k) * N;
            if (n4) {
                bv = (nn < N) ? *(const float4*)(brow + nn) : make_float4(0.f,0.f,0.f,0.f);
            } else {
                bv.x = (nn + 0 < N) ? brow[nn + 0] : 0.f;
                bv.y = (nn + 1 < N) ? brow[nn + 1] : 0.f;
                bv.z = (nn + 2 < N) ? brow[nn + 2] : 0.f;
                bv.w = (nn + 3 < N) ? brow[nn + 3] : 0.f;
            }
        }
        __syncthreads();
        As[a_k + 0][a_m] = av.x;
        As[a_k + 1][a_m] = av.y;
        As[a_k + 2][a_m] = av.z;
        As[a_k + 3][a_m] = av.w;
        *(float4*)&Bs[b_k][b_n] = bv;
        __syncthreads();
#pragma unroll
        for (int k = 0; k < 16; k++) {
            float4 a4 = *(const float4*)&As[k][tm];
            float4 b4 = *(const float4*)&Bs[k][tn];
            acc[0][0] = fmaf(a4.x, b4.x, acc[0][0]);
            acc[0][1] = fmaf(a4.x, b4.y, acc[0][1]);
            acc[0][2] = fmaf(a4.x, b4.z, acc[0][2]);
            acc[0][3] = fmaf(a4.x, b4.w, acc[0][3]);
            acc[1][0] = fmaf(a4.y, b4.x, acc[1][0]);
            acc[1][1] = fmaf(a4.y, b4.y, acc[1][1]);
            acc[1][2] = fmaf(a4.y, b4.z, acc[1][2]);
            acc[1][3] = fmaf(a4.y, b4.w, acc[1][3]);
            acc[2][0] = fmaf(a4.z, b4.x, acc[2][0]);
            acc[2][1] = fmaf(a4.z, b4.y, acc[2][1]);
            acc[2][2] = fmaf(a4.z, b4.z, acc[2][2]);
            acc[2][3] = fmaf(a4.z, b4.w, acc[2][3]);
            acc[3][0] = fmaf(a4.w, b4.x, acc[3][0]);
            acc[3][1] = fmaf(a4.w, b4.y, acc[3][1]);
            acc[3][2] = fmaf(a4.w, b4.z, acc[3][2]);
            acc[3][3] = fmaf(a4.w, b4.w, acc[3][3]);
        }
    }

    if (direct) {
#pragma unroll
        for (int i = 0; i < 4; i++) {
            const int m = m0 + tm + i;
            const size_t row = (size_t)m * ldc;
#pragma unroll
            for (int j = 0; j < 4; j++) {
                const int n = n0 + tn + j;
                if (n < N) {
                    float v = acc[i][j] + (bias ? bias[n] : 0.f);
                    if (act == 1) v = fast_tanh(v);
                    else if (act == 2) v = fast_sig(v);
                    C[row + n] = v;
                }
            }
        }
    } else {
        float* Pp = C + (size_t)s * 64 * N;
#pragma unroll
        for (int i = 0; i < 4; i++) {
#pragma unroll
            for (int j = 0; j < 4; j++) {
                const int n = n0 + tn + j;
                if (n < N) Pp[(size_t)(tm + i) * N + n] = acc[i][j];
            }
        }
    }
}

// fallback big GEMM (round-3, validated)
__global__ __launch_bounds__(256) void gemm_mfma3(
    const float* __restrict__ A, const float* __restrict__ B,
    const float* __restrict__ bias, float* __restrict__ C,
    int M, int N, int K, int lda, int ldb, int ldc, int pmap)
{
    __shared__ short Ah[128 * 40], Al[128 * 40];
    __shared__ short Bh[128 * 40], Bl[128 * 40];

    const int tid = threadIdx.x;
    const int n0  = blockIdx.x * 128;
    const int m0  = blockIdx.y * 128;

    const int lane = tid & 63;
    const int w    = tid >> 6;
    const int wm   = (w >> 1) * 64;
    const int wn   = (w & 1) * 64;
    const int lm   = lane & 15;
    const int lk   = lane >> 4;

    const int ar = tid >> 1;
    const int ac = (tid & 1) * 16;
    const int kb = (tid & 15) * 2;
    const int c8 = (tid >> 4) * 8;

    const bool bvec = ((ldb & 3) == 0) && (n0 + 128 <= N);

    f32x4 acc[4][4];
#pragma unroll
    for (int i = 0; i < 4; i++)
#pragma unroll
        for (int j = 0; j < 4; j++) acc[i][j] = (f32x4)0.f;

    for (int k0 = 0; k0 < K; k0 += 32) {
        float f[16];
        if (m0 + ar < M) {
            const float* ap = A + (size_t)(m0 + ar) * lda + (k0 + ac);
            float4 q0 = *(const float4*)(ap);
            float4 q1 = *(const float4*)(ap + 4);
            float4 q2 = *(const float4*)(ap + 8);
            float4 q3 = *(const float4*)(ap + 12);
            f[0]=q0.x; f[1]=q0.y; f[2]=q0.z; f[3]=q0.w;
            f[4]=q1.x; f[5]=q1.y; f[6]=q1.z; f[7]=q1.w;
            f[8]=q2.x; f[9]=q2.y; f[10]=q2.z; f[11]=q2.w;
            f[12]=q3.x; f[13]=q3.y; f[14]=q3.z; f[15]=q3.w;
        } else {
#pragma unroll
            for (int j = 0; j < 16; j++) f[j] = 0.f;
        }
        bf16x8 h0, h1, l0, l1;
#pragma unroll
        for (int j = 0; j < 8; j++) {
            short hh, ll;
            split_bf(f[j], hh, ll);     h0[j] = hh; l0[j] = ll;
            split_bf(f[8 + j], hh, ll); h1[j] = hh; l1[j] = ll;
        }
        float g0[8], g1[8];
        if (bvec) {
            const float* bp0 = B + (size_t)(k0 + kb) * ldb + (n0 + c8);
            const float* bp1 = bp0 + ldb;
            float4 q0 = *(const float4*)(bp0);
            float4 q1 = *(const float4*)(bp0 + 4);
            float4 q2 = *(const float4*)(bp1);
            float4 q3 = *(const float4*)(bp1 + 4);
            g0[0]=q0.x; g0[1]=q0.y; g0[2]=q0.z; g0[3]=q0.w;
            g0[4]=q1.x; g0[5]=q1.y; g0[6]=q1.z; g0[7]=q1.w;
            g1[0]=q2.x; g1[1]=q2.y; g1[2]=q2.z; g1[3]=q2.w;
            g1[4]=q3.x; g1[5]=q3.y; g1[6]=q3.z; g1[7]=q3.w;
        } else {
            const float* bp0 = B + (size_t)(k0 + kb) * ldb;
            const float* bp1 = bp0 + ldb;
#pragma unroll
            for (int j = 0; j < 8; j++) {
                const int nn = n0 + c8 + j;
                g0[j] = (nn < N) ? bp0[nn] : 0.f;
                g1[j] = (nn < N) ? bp1[nn] : 0.f;
            }
        }
        __syncthreads();
        *(bf16x8*)&Ah[ar * 40 + ac]     = h0;
        *(bf16x8*)&Ah[ar * 40 + ac + 8] = h1;
        *(bf16x8*)&Al[ar * 40 + ac]     = l0;
        *(bf16x8*)&Al[ar * 40 + ac + 8] = l1;
#pragma unroll
        for (int j = 0; j < 8; j++) {
            short ha, la, hb, lb;
            split_bf(g0[j], ha, la);
            split_bf(g1[j], hb, lb);
            const int ci = (c8 + j) * 40 + kb;
            *(int*)&Bh[ci] = (int)((unsigned short)ha | ((unsigned)(unsigned short)hb << 16));
            *(int*)&Bl[ci] = (int)((unsigned short)la | ((unsigned)(unsigned short)lb << 16));
        }
        __syncthreads();

        bf16x8 afh[4], afl[4], bfh[4], bfl[4];
#pragma unroll
        for (int fm = 0; fm < 4; fm++) {
            const int idx = (wm + fm * 16 + lm) * 40 + lk * 8;
            afh[fm] = *(bf16x8*)&Ah[idx];
            afl[fm] = *(bf16x8*)&Al[idx];
        }
#pragma unroll
        for (int fn = 0; fn < 4; fn++) {
            const int idx = (wn + fn * 16 + lm) * 40 + lk * 8;
            bfh[fn] = *(bf16x8*)&Bh[idx];
            bfl[fn] = *(bf16x8*)&Bl[idx];
        }
#pragma unroll
        for (int fm = 0; fm < 4; fm++)
#pragma unroll
            for (int fn = 0; fn < 4; fn++) {
                acc[fm][fn] = __builtin_amdgcn_mfma_f32_16x16x32_bf16(afh[fm], bfh[fn], acc[fm][fn], 0, 0, 0);
                acc[fm][fn] = __builtin_amdgcn_mfma_f32_16x16x32_bf16(afh[fm], bfl[fn], acc[fm][fn], 0, 0, 0);
                acc[fm][fn] = __builtin_amdgcn_mfma_f32_16x16x32_bf16(afl[fm], bfh[fn], acc[fm][fn], 0, 0, 0);
            }
    }

#pragma unroll
    for (int fm = 0; fm < 4; fm++) {
#pragma unroll
        for (int fn = 0; fn < 4; fn++) {
            const int col = n0 + wn + fn * 16 + lm;
            if (col >= N) continue;
            const float bb = bias ? bias[col] : 0.f;
#pragma unroll
            for (int r = 0; r < 4; r++) {
                const int row = m0 + wm + fm * 16 + lk * 4 + r;
                if (row >= M) continue;
                const size_t orow = pmap ? (size_t)((row & 63) * TSTEPS + (row >> 6))
                                         : (size_t)row;
                C[orow * ldc + col] = acc[fm][fn][r] + bb;
            }
        }
    }
}

__global__ __launch_bounds__(256) void reduce_partials(
    const float* __restrict__ P, int S, int N,
    const float* __restrict__ bias, float* __restrict__ C, int ldc, int act)
{
    const int idx = blockIdx.x * 256 + threadIdx.x;
    const int total = 64 * N;
    if (idx >= total) return;
    const int m = idx / N;
    const int n = idx - m * N;
    float v = bias ? bias[n] : 0.f;
    for (int s = 0; s < S; s++) v += P[(size_t)s * total + idx];
    if (act == 1) v = fast_tanh(v);
    else if (act == 2) v = fast_sig(v);
    else if (act == 3 && n >= RNND) v = fast_sig(v);
    C[(size_t)m * ldc + n] = v;
}

__global__ __launch_bounds__(256) void reduce_lstm(
    const float* __restrict__ P, int S, const float* __restrict__ bsum,
    float* __restrict__ hn, float* __restrict__ c,
    short* __restrict__ hbh, short* __restrict__ hbl)
{
    const int idx = blockIdx.x * 256 + threadIdx.x;
    const int b = idx >> 10, r = idx & 1023;
    const float* pb = P + (size_t)b * 4096;
    float gi = bsum[r], gf = bsum[1024 + r], gg = bsum[2048 + r], go = bsum[3072 + r];
    for (int s = 0; s < S; s++) {
        const float* q = pb + (size_t)s * 64 * 4096;
        gi += q[r]; gf += q[1024 + r]; gg += q[2048 + r]; go += q[3072 + r];
    }
    const float ig = fast_sig(gi);
    const float fg = fast_sig(gf);
    const float g2 = fast_tanh(gg);
    const float og = fast_sig(go);
    const float cn = fg * c[idx] + ig * g2;
    const float hv = og * fast_tanh(cn);
    c[idx]  = cn;
    hn[idx] = hv;
    if (hbh) {
        short hi, lo;
        split_bf(hv, hi, lo);
        hbh[idx] = hi;
        hbl[idx] = lo;
    }
}

__global__ __launch_bounds__(256) void mean_img(
    const float* __restrict__ img, float* __restrict__ avg)
{
    const int b = blockIdx.x;
    const int d = blockIdx.y * 256 + threadIdx.x;
    const float* p = img + (size_t)b * LIMG * DIMG + d;
    float s = 0.f;
    for (int l = 0; l < LIMG; l++) s += p[(size_t)l * DIMG];
    avg[(size_t)b * DIMG + d] = s * (1.f / 196.f);
}

__global__ __launch_bounds__(256) void concat_w(
    const float* __restrict__ WU, const float* __restrict__ Wfb,
    float* __restrict__ Wug)
{
    const int idx = blockIdx.x * 256 + threadIdx.x;
    if (idx >= 1024 * 3072) return;
    const int k = idx / 3072;
    const int j = idx - k * 3072;
    Wug[idx] = (j < 1024) ? WU[(size_t)k * 1024 + j] : Wfb[(size_t)k * 2048 + (j - 1024)];
}

__global__ __launch_bounds__(256) void concat_b(
    const float* __restrict__ bU, const float* __restrict__ bfb,
    const float* __restrict__ bih, const float* __restrict__ bhh,
    float* __restrict__ bug, float* __restrict__ bsum)
{
    const int j = blockIdx.x * 256 + threadIdx.x;
    if (j < 3072) bug[j] = (j < 1024) ? bU[j] : bfb[j - 1024];
    if (j < 4096) bsum[j] = bih[j] + bhh[j];
}

__global__ __launch_bounds__(256) void attn_e(
    const float* __restrict__ Ws, const float* __restrict__ ug,
    const float* __restrict__ Wv, const float* __restrict__ bv,
    float* __restrict__ e)
{
    const int wv   = (blockIdx.x << 2) + (threadIdx.x >> 6);
    const int lane = threadIdx.x & 63;
    const int b    = wv / LIMG;
    const float* wrow = Ws + (size_t)wv * RNND;
    const float* urow = ug + (size_t)b * 3072;
    float acc = 0.f;
#pragma unroll
    for (int k = lane * 4; k < RNND; k += 256) {
        float4 wq = *(const float4*)(wrow + k);
        float4 uq = *(const float4*)(urow + k);
        float4 vq = *(const float4*)(Wv + k);
        acc += fast_tanh(wq.x + uq.x) * vq.x + fast_tanh(wq.y + uq.y) * vq.y
             + fast_tanh(wq.z + uq.z) * vq.z + fast_tanh(wq.w + uq.w) * vq.w;
    }
#pragma unroll
    for (int off = 32; off > 0; off >>= 1) acc += __shfl_down(acc, off);
    if (lane == 0) e[wv] = acc + bv[0];
}

// ---------------------------------------------------------------------------
// Fused softmax + alphas write + x assembly (emb | gate*ctx | h).
// grid (64, 5): y==0 handles emb/h/alphas; y in 1..4 handles 512-wide ctx.
// Softmax recomputed per block from e (cheap, removes one kernel launch).
// ---------------------------------------------------------------------------
__global__ __launch_bounds__(256) void ctx_fuse(
    const float* __restrict__ e, const float* __restrict__ img,
    const float* __restrict__ ug, const float* __restrict__ embt,
    const int* __restrict__ captions, const float* __restrict__ h,
    float* __restrict__ x, float* __restrict__ alphas_out, int t)
{
    __shared__ float al[256];
    __shared__ float red[256];
    const int b = blockIdx.x, y = blockIdx.y, tid = threadIdx.x;

    const float v = (tid < LIMG) ? e[b * LIMG + tid] : -3.0e38f;
    red[tid] = v; __syncthreads();
    for (int s = 128; s > 0; s >>= 1) {
        if (tid < s) red[tid] = fmaxf(red[tid], red[tid + s]);
        __syncthreads();
    }
    const float mx = red[0]; __syncthreads();
    const float ex = (tid < LIMG) ? __expf(v - mx) : 0.f;
    red[tid] = ex; __syncthreads();
    for (int s = 128; s > 0; s >>= 1) {
        if (tid < s) red[tid] += red[tid + s];
        __syncthreads();
    }
    const float inv = 1.f / red[0];
    al[tid] = ex * inv;
    __syncthreads();

    if (y == 0) {
        if (tid < LIMG)
            alphas_out[(size_t)b * (TSTEPS * LIMG) + t * LIMG + tid] = al[tid];
        const int tok = (t == 0) ? 10001 : captions[b * 16 + (t - 1)];
        for (int j = tid; j < EMBD; j += 256)
            x[(size_t)b * 3584 + j] = embt[(size_t)tok * EMBD + j];
        for (int j = tid; j < RNND; j += 256)
            x[(size_t)b * 3584 + 2560 + j] = h[(size_t)b * RNND + j];
    } else {
        const int d0 = (y - 1) * 512 + tid * 2;
        const float* ib = img + (size_t)b * LIMG * DIMG + d0;
        float a0 = 0.f, a1 = 0.f;
#pragma unroll 4
        for (int l = 0; l < LIMG; l++) {
            float2 q = *(const float2*)(ib + (size_t)l * DIMG);
            a0 = fmaf(al[l], q.x, a0);
            a1 = fmaf(al[l], q.y, a1);
        }
        const float g0 = ug[(size_t)b * 3072 + 1024 + d0];
        const float g1 = ug[(size_t)b * 3072 + 1024 + d0 + 1];
        x[(size_t)b * 3584 + EMBD + d0]     = g0 * a0;
        x[(size_t)b * 3584 + EMBD + d0 + 1] = g1 * a1;
    }
}

__global__ __launch_bounds__(256) void softmax_alpha(
    const float* __restrict__ e, float* __restrict__ alpha,
    float* __restrict__ alphas_out, int t)
{
    __shared__ float red[256];
    const int b = blockIdx.x, tid = threadIdx.x;
    const float v = (tid < LIMG) ? e[b * LIMG + tid] : -3.0e38f;
    red[tid] = v; __syncthreads();
    for (int s = 128; s > 0; s >>= 1) {
        if (tid < s) red[tid] = fmaxf(red[tid], red[tid + s]);
        __syncthreads();
    }
    const float mx = red[0]; __syncthreads();
    const float ex = (tid < LIMG) ? __expf(v - mx) : 0.f;
    red[tid] = ex; __syncthreads();
    for (int s = 128; s > 0; s >>= 1) {
        if (tid < s) red[tid] += red[tid + s];
        __syncthreads();
    }
    const float inv = 1.f / red[0];
    if (tid < LIMG) {
        const float a = ex * inv;
        alpha[b * LIMG + tid] = a;
        alphas_out[(size_t)b * (TSTEPS * LIMG) + t * LIMG + tid] = a;
    }
}

__global__ __launch_bounds__(128) void assemble_x(
    const float* __restrict__ img, const float* __restrict__ alpha,
    const float* __restrict__ ug, const float* __restrict__ emb,
    const int* __restrict__ captions, const float* __restrict__ h,
    float* __restrict__ x, int t, int stride)
{
    const int b = blockIdx.x, y = blockIdx.y, tid = threadIdx.x;
    if (y < 4) {
        const int tok = (t == 0) ? 10001 : captions[b * 16 + (t - 1)];
        const int j = y * 128 + tid;
        x[(size_t)b * stride + j] = emb[(size_t)tok * EMBD + j];
    } else if (y < 20) {
        __shared__ float al[LIMG];
        for (int i = tid; i < LIMG; i += 128) al[i] = alpha[b * LIMG + i];
        __syncthreads();
        const int d = (y - 4) * 128 + tid;
        const float* ib = img + (size_t)b * LIMG * DIMG + d;
        float accv = 0.f;
#pragma unroll 4
        for (int l = 0; l < LIMG; l++) accv = fmaf(al[l], ib[(size_t)l * DIMG], accv);
        const float g = ug[(size_t)b * 3072 + 1024 + d];
        x[(size_t)b * stride + EMBD + d] = g * accv;
    } else {
        const int j = (y - 20) * 128 + tid;
        x[(size_t)b * stride + 2560 + j] = h[(size_t)b * RNND + j];
    }
}

extern "C" void kernel_launch(void* const* d_in, const int* in_sizes, int n_in,
                              void* d_out, int out_size, void* d_ws, size_t ws_size,
                              hipStream_t stream)
{
    const float* img      = (const float*)d_in[0];
    const int*   captions = (const int*)d_in[1];
    const float* emb      = (const float*)d_in[2];
    const float* Wih      = (const float*)d_in[3];
    const float* Whh      = (const float*)d_in[4];
    const float* bih      = (const float*)d_in[5];
    const float* bhh      = (const float*)d_in[6];
    const float* Wh0      = (const float*)d_in[7];
    const float* bh0      = (const float*)d_in[8];
    const float* Wc0      = (const float*)d_in[9];
    const float* bc0      = (const float*)d_in[10];
    const float* Wfb      = (const float*)d_in[11];
    const float* bfb      = (const float*)d_in[12];
    const float* Wout     = (const float*)d_in[13];
    const float* bout     = (const float*)d_in[14];
    const float* WU       = (const float*)d_in[15];
    const float* bU       = (const float*)d_in[16];
    const float* WW       = (const float*)d_in[17];
    const float* bW       = (const float*)d_in[18];
    const float* Wv       = (const float*)d_in[19];
    const float* bv       = (const float*)d_in[20];

    float* preds      = (float*)d_out;
    float* alphas_out = preds + (size_t)NB * TSTEPS * VOUTD;

    const size_t NEED = 190000000;

    if (ws_size >= NEED) {
        float* w = (float*)d_ws;
        float* Ws    = w; w += (size_t)12544 * 1024;
        float* ug    = w; w += (size_t)64 * 3072;
        float* P     = w; w += (size_t)8 * 64 * 4096;
        float* e     = w; w += (size_t)64 * LIMG;
        float* alpha = w; w += (size_t)64 * LIMG;
        float* xh    = w; w += (size_t)64 * 3584;
        float* h     = w; w += (size_t)64 * RNND;
        float* c     = w; w += (size_t)64 * RNND;
        float* avg   = w; w += (size_t)64 * DIMG;
        float* bsum  = w; w += 4096;
        float* bug   = w; w += 3072;
        short* u = (short*)w;
        short* Hbh     = u; u += (size_t)1280 * 1024;
        short* Hbl     = u; u += (size_t)1280 * 1024;
        short* WWTh    = u; u += (size_t)1024 * 2048;
        short* WWTl    = u; u += (size_t)1024 * 2048;
        short* WugTh   = u; u += (size_t)3072 * 1024;
        short* WugTl   = u; u += (size_t)3072 * 1024;
        short* WfullTh = u; u += (size_t)4096 * 3584;
        short* WfullTl = u; u += (size_t)4096 * 3584;
        short* WoutTh  = u; u += (size_t)10112 * 1024;
        short* WoutTl  = u; u += (size_t)10112 * 1024;

        mean_img<<<dim3(NB, 8), 256, 0, stream>>>(img, avg);
        gemm64<<<dim3(16, 1, 8), 256, 0, stream>>>(avg, Wh0, nullptr, P, 1024, 2048, 256, 0, 0, 0);
        reduce_partials<<<256, 256, 0, stream>>>(P, 8, 1024, bh0, h, 1024, 1);
        gemm64<<<dim3(16, 1, 8), 256, 0, stream>>>(avg, Wc0, nullptr, P, 1024, 2048, 256, 0, 0, 0);
        reduce_partials<<<256, 256, 0, stream>>>(P, 8, 1024, bc0, c, 1024, 1);
        concat_b<<<16, 256, 0, stream>>>(bU, bfb, bih, bhh, bug, bsum);

        tsplit<<<dim3(32, 16), 256, 0, stream>>>(WW, 1024, WW, 1024, WWTh, WWTl, 1024, 2048, 2048, 0);
        tsplit<<<dim3(16, 48), 256, 0, stream>>>(WU, 1024, Wfb, 2048, WugTh, WugTl, 3072, 1024, 1024, 1024);
        tsplit<<<dim3(56, 64), 256, 0, stream>>>(Wih, 4096, Whh, 4096, WfullTh, WfullTl, 4096, 3584, 2560, 0);
        tsplit<<<dim3(16, 157), 256, 0, stream>>>(Wout, VOUTD, Wout, VOUTD, WoutTh, WoutTl, VOUTD, 1024, 1024, 0);

        // W_s = img @ WW + bW : group by m-panel (A=img L2 reuse). G=98,O=8 -> 8*13*8=832
        gemm_bb<<<832, 256, 0, stream>>>(img, nullptr, nullptr, WWTh, WWTl,
                                         bW, Ws, 12544, 1024, 2048, 2048, 2048, 1024, 0,
                                         8, 98, 1);

        for (int t = 0; t < TSTEPS; t++) {
            gemm_sk<<<dim3(24, 1, 8), 256, 0, stream>>>(h, WugTh, WugTl, P, 3072, 1024, 1024, 1024, 128);
            reduce_partials<<<768, 256, 0, stream>>>(P, 8, 3072, bug, ug, 3072, 3);
            attn_e<<<3136, 256, 0, stream>>>(Ws, ug, Wv, bv, e);
            ctx_fuse<<<dim3(NB, 5), 256, 0, stream>>>(e, img, ug, emb, captions, h, xh, alphas_out, t);
            gemm_sk<<<dim3(32, 1, 7), 256, 0, stream>>>(xh, WfullTh, WfullTl, P, 4096, 3584, 3584, 3584, 512);
            reduce_lstm<<<256, 256, 0, stream>>>(P, 7, bsum, h, c,
                                                 Hbh + (size_t)(t + 1) * 65536,
                                                 Hbl + (size_t)(t + 1) * 65536);
        }

        // preds: group by n-panel (B=Wout L2 reuse). G=79,O=9 -> 8*10*9=720
        gemm_bb<<<720, 256, 0, stream>>>(nullptr, Hbh + 65536, Hbl + 65536,
                                         WoutTh, WoutTl, bout, preds,
                                         1088, VOUTD, 1024, 1024, 1024, VOUTD, 1,
                                         79, 9, 0);
    } else {
        float* w = (float*)d_ws;
        float* Ws    = w; w += (size_t)12544 * 1024;
        float* ug    = w; w += (size_t)64 * 3072;
        float* P     = w; w += (size_t)12 * 64 * 4096;
        float* e     = w; w += (size_t)64 * LIMG;
        float* alpha = w; w += (size_t)64 * LIMG;
        float* x     = w; w += (size_t)64 * 2560;
        float* Hh    = w; w += (size_t)18 * 64 * RNND;
        float* c     = w; w += (size_t)64 * RNND;
        float* avg   = w; w += (size_t)64 * DIMG;
        float* bsum  = w; w += 4096;
        float* Wug   = w; w += (size_t)1024 * 3072;
        float* bug   = w; w += 3072;

        mean_img<<<dim3(NB, 8), 256, 0, stream>>>(img, avg);
        gemm64<<<dim3(16, 1, 8), 256, 0, stream>>>(avg, Wh0, nullptr, P, 1024, 2048, 256, 0, 0, 0);
        reduce_partials<<<256, 256, 0, stream>>>(P, 8, 1024, bh0, Hh, 1024, 1);
        gemm64<<<dim3(16, 1, 8), 256, 0, stream>>>(avg, Wc0, nullptr, P, 1024, 2048, 256, 0, 0, 0);
        reduce_partials<<<256, 256, 0, stream>>>(P, 8, 1024, bc0, c, 1024, 1);
        concat_b<<<16, 256, 0, stream>>>(bU, bfb, bih, bhh, bug, bsum);
        concat_w<<<12288, 256, 0, stream>>>(WU, Wfb, Wug);
        gemm_mfma3<<<dim3(8, 98), 256, 0, stream>>>(img, WW, bW, Ws,
                                                    12544, 1024, 2048, 2048, 1024, 1024, 0);
        for (int t = 0; t < TSTEPS; t++) {
            const float* hc = Hh + (size_t)t * 64 * RNND;
            float*       hn = Hh + (size_t)(t + 1) * 64 * RNND;
            gemm64<<<dim3(48, 1, 8), 256, 0, stream>>>(hc, Wug, nullptr, P, 3072, 1024, 128, 0, 0, 0);
            reduce_partials<<<768, 256, 0, stream>>>(P, 8, 3072, bug, ug, 3072, 3);
            attn_e<<<3136, 256, 0, stream>>>(Ws, ug, Wv, bv, e);
            softmax_alpha<<<NB, 256, 0, stream>>>(e, alpha, alphas_out, t);
            assemble_x<<<dim3(NB, 20), 128, 0, stream>>>(img, alpha, ug, emb, captions, hc, x, t, 2560);
            gemm64<<<dim3(64, 1, 8), 256, 0, stream>>>(x, Wih, nullptr, P, 4096, 2560, 320, 0, 0, 0);
            gemm64<<<dim3(64, 1, 4), 256, 0, stream>>>(hc, Whh, nullptr, P + (size_t)8 * 64 * 4096,
                                                       4096, 1024, 256, 0, 0, 0);
            reduce_lstm<<<256, 256, 0, stream>>>(P, 12, bsum, hn, c, nullptr, nullptr);
        }
        gemm_mfma3<<<dim3(79, 9), 256, 0, stream>>>(Hh + (size_t)64 * RNND, Wout, bout, preds,
                                                    TSTEPS * 64, VOUTD, 1024, 1024, VOUTD, VOUTD, 1);
    }
}